// Round 5
// baseline (649.645 us; speedup 1.0000x reference)
//
#include <hip/hip_runtime.h>
#include <hip/hip_bf16.h>
#include <math.h>
#include <stdint.h>

typedef __attribute__((ext_vector_type(4))) float floatx4;
typedef __attribute__((ext_vector_type(8))) short shortx8;
typedef __attribute__((ext_vector_type(4))) unsigned short ushortx4;

#define BS_CAND 4096   // B*S
#define HDIM    1024
#define MSLOTS  8192
#define THRESH  64.0f
#define PV_SPLIT 4
#define PS_COLS 128    // 32 bn-tiles x 4 n-waves

__device__ __forceinline__ unsigned short f2b_bits(float f) {
    __hip_bfloat16 b = __float2bfloat16(f);
    return *(unsigned short*)&b;
}
__device__ __forceinline__ float b2f_bits(unsigned short u) {
    return __uint_as_float(((unsigned)u) << 16);
}

// ---------------- reduction helper (blockDim == 256) ----------------
__device__ __forceinline__ float blockReduceSum(float x) {
    __shared__ float red[4];
    #pragma unroll
    for (int o = 32; o > 0; o >>= 1) x += __shfl_down(x, o, 64);
    int lane = threadIdx.x & 63, w = threadIdx.x >> 6;
    if (lane == 0) red[w] = x;
    __syncthreads();
    float s = red[0] + red[1] + red[2] + red[3];
    __syncthreads();
    return s;
}

// ------- merged prologue: norm+cast of hidden | slot keys | Wq/Wk cast -------
__global__ __launch_bounds__(256) void pre_k(const float* __restrict__ h,
                                             float* __restrict__ sur,
                                             __hip_bfloat16* __restrict__ Hbf,
                                             const float* __restrict__ imp,
                                             const float* __restrict__ noi,
                                             float* __restrict__ keys,
                                             int* __restrict__ row_src,
                                             const float* __restrict__ Wq,
                                             __hip_bfloat16* __restrict__ Wqbf,
                                             const float* __restrict__ Wk,
                                             __hip_bfloat16* __restrict__ Wkbf) {
    int b = blockIdx.x;
    if (b < BS_CAND) {
        float4 v = ((const float4*)(h + (size_t)b * HDIM))[threadIdx.x];
        ushortx4 o;
        o.x = f2b_bits(v.x); o.y = f2b_bits(v.y);
        o.z = f2b_bits(v.z); o.w = f2b_bits(v.w);
        ((ushortx4*)(Hbf + (size_t)b * HDIM))[threadIdx.x] = o;
        float s = v.x * v.x + v.y * v.y + v.z * v.z + v.w * v.w;
        float tot = blockReduceSum(s);
        if (threadIdx.x == 0) sur[b] = 2.0f * sqrtf(tot);
    } else if (b < BS_CAND + MSLOTS / 256) {
        int i = (b - BS_CAND) * 256 + threadIdx.x;
        keys[i] = imp[i] + noi[i] * 1e-6f;
        row_src[i] = -1;
    } else {
        int w = b - (BS_CAND + MSLOTS / 256);          // 0..2047
        const float* in = (w < 1024) ? Wq : Wk;
        __hip_bfloat16* out = (w < 1024) ? Wqbf : Wkbf;
        int j = (w & 1023) * 256 + threadIdx.x;        // float4 index
        float4 v = ((const float4*)in)[j];
        ushortx4 o;
        o.x = f2b_bits(v.x); o.y = f2b_bits(v.y);
        o.z = f2b_bits(v.z); o.w = f2b_bits(v.w);
        ((ushortx4*)out)[j] = o;
    }
}

// ---------------- merged ranks: one BLOCK per element ----------------
__global__ __launch_bounds__(256) void ranks_k(const float* __restrict__ sur,
                                               int* __restrict__ cand_ord,
                                               const float* __restrict__ keys,
                                               int* __restrict__ slot_ord) {
    int b = blockIdx.x;
    if (b < BS_CAND) {
        float ki = sur[b];
        float cnt = 0.f;
        for (int j = threadIdx.x; j < BS_CAND; j += 256) {
            float kj = sur[j];
            cnt += ((kj > ki) || (kj == ki && j < b)) ? 1.f : 0.f;
        }
        float r = blockReduceSum(cnt);
        if (threadIdx.x == 0) cand_ord[(int)r] = b;
    } else {
        int i = b - BS_CAND;
        float ki = keys[i];
        float cnt = 0.f;
        for (int j = threadIdx.x; j < MSLOTS; j += 256) {
            float kj = keys[j];
            cnt += ((kj < ki) || (kj == ki && j < i)) ? 1.f : 0.f;
        }
        float r = blockReduceSum(cnt);
        if (threadIdx.x == 0) slot_ord[(int)r] = i;
    }
}

// ---------------- scatter: rank-i candidate -> rank-i least-important slot ----
__global__ __launch_bounds__(256) void scatter_k(const int* __restrict__ cand_order,
                                                 const int* __restrict__ slot_order,
                                                 const float* __restrict__ sur,
                                                 int* __restrict__ row_src) {
    int i = blockIdx.x * 256 + threadIdx.x;   // i < BS_CAND
    int c = cand_order[i];
    if (sur[c] > THRESH) row_src[slot_order[i]] = c;
}

// ------ merged build+transpose: Bbf row-major AND BbfT, one pass ------
__global__ __launch_bounds__(256) void bbt_k(const float* __restrict__ mem,
                                             const float* __restrict__ hid,
                                             const int* __restrict__ src,
                                             __hip_bfloat16* __restrict__ B,
                                             __hip_bfloat16* __restrict__ BT) {
    __shared__ unsigned short t[64][72];
    int cb = blockIdx.x * 64, rb = blockIdx.y * 64;
    int tx = threadIdx.x & 63, ty = threadIdx.x >> 6;
    #pragma unroll
    for (int k = 0; k < 16; k++) {
        int r = ty * 16 + k;
        int s = src[rb + r];
        const float* row = (s < 0) ? (mem + (size_t)(rb + r) * HDIM)
                                   : (hid + (size_t)s * HDIM);
        unsigned short b = f2b_bits(row[cb + tx]);
        t[r][tx] = b;
        ((unsigned short*)B)[(size_t)(rb + r) * HDIM + cb + tx] = b;
    }
    __syncthreads();
    #pragma unroll
    for (int k = 0; k < 16; k++) {
        int c = ty * 16 + k;
        ((unsigned short*)BT)[(size_t)(cb + c) * MSLOTS + rb + tx] = t[tx][c];
    }
}

// ---------------- async global->LDS helper ----------------
__device__ __forceinline__ void load_lds16(const __hip_bfloat16* g, __hip_bfloat16* l) {
    __builtin_amdgcn_global_load_lds(
        (const __attribute__((address_space(1))) void*)g,
        (__attribute__((address_space(3))) void*)l, 16, 0, 0);
}

// =====================================================================
// 256x256 8-phase BT-GEMM, register-PIPELINED (T2+T3+T4+T5 + read-ahead):
// r1-verified stage schedule / vmcnt(6) discipline / swizzle UNCHANGED.
// NEW: ds_reads for phase p+1 issue during phase p (counted lgkmcnt(n)
// at p+1 drains them); the 12-read bursts sit in the read-empty phases
// ph4/ph8 AFTER the {vmcnt;barrier} pair (their regions' DMA-landing
// guarantee) and overlap that phase's MFMA. Register sets:
//   afX/afY : A-fragment double buffer (32 VGPR each)
//   bQ0/bQ1/bR0 : B halves (bQ1 doubles as tile-1 B1)   (16 VGPR each)
// Per-phase issue counts -> lgkm immediates:
//   ph1:4  ph2:8  ph3:0  ph4:12(post-bar)  ph5:4  ph6:8  ph7:0  ph8:12
// Hazards re-proven: every STAGE(R) >= 1 barrier after all waves' last
// read of R drained (reads at q drain at q+1's counted lgkm, before
// q+1's end-barrier; stages unchanged at >= q+2). DMA-RAW: reads of a
// region staged at q issue only after a {vmcnt<=6 covering q; barrier}.
// EPI 1/2/4 as before.
// =====================================================================
template <int EPI, int SWAP>
__global__ __launch_bounds__(512, 2) void gemm_bt(const __hip_bfloat16* __restrict__ A,
                                                  const __hip_bfloat16* __restrict__ Bt,
                                                  const __hip_bfloat16* __restrict__ Bt2,
                                                  __hip_bfloat16* __restrict__ outH,
                                                  const float* __restrict__ bias,
                                                  const float* __restrict__ bias2,
                                                  float* __restrict__ ps,
                                                  int rows0b,
                                                  int M, int N, int K, int ksplit,
                                                  float scale) {
    extern __shared__ char lds[];
    const int tid = threadIdx.x;
    const int wave = tid >> 6, lane = tid & 63;
    const int lm = lane & 15, lq = lane >> 4;
    const int wm = wave >> 2, wn = wave & 3;
    const int bm = SWAP ? blockIdx.x : blockIdx.y;
    const int bn = SWAP ? blockIdx.y : blockIdx.x;
    const int kb = blockIdx.z * ksplit;
    const int niters = ksplit >> 7;            // 128 of K per iteration

    const __hip_bfloat16* BtSel = (EPI == 1 && bm >= rows0b) ? Bt2 : Bt;
    const float* biasSel = (EPI == 1 && bm >= rows0b) ? bias2 : bias;

    // ---- per-thread staging source pointers (pre-swizzled global src) ----
    const int l8 = lane >> 3;
    const int colsrc = ((((lane & 7) << 4) ^ (l8 << 4)) >> 1);
    const __hip_bfloat16* Abase = A + (size_t)bm * 256 * K;
    const __hip_bfloat16* Bbase = BtSel + (size_t)bn * 256 * K;
    const __hip_bfloat16* srcA[2][2];
    const __hip_bfloat16* srcB[2][2];
    #pragma unroll
    for (int h = 0; h < 2; h++)
        #pragma unroll
        for (int t = 0; t < 2; t++) {
            int row = t * 128 + h * 64 + wave * 8 + l8;
            srcA[h][t] = Abase + (size_t)row * K + colsrc;
            srcB[h][t] = Bbase + (size_t)row * K + colsrc;
        }

    // ---- ds_read fragment byte offsets (swizzled) ----
    const int cxor = (lq << 4) ^ ((lm & 7) << 4);
    const int a_b0 = (wm * 64 + lm) * 128 + cxor;
    const int a_b1 = a_b0 ^ 64;
    const int b_b0 = (wn * 32 + lm) * 128 + cxor;
    const int b_b1 = b_b0 ^ 64;

    floatx4 acc[8][4];
    #pragma unroll
    for (int i = 0; i < 8; i++)
        #pragma unroll
        for (int j = 0; j < 4; j++) acc[i][j] = {0.f, 0.f, 0.f, 0.f};

    shortx8 afX[4][2], afY[4][2];          // A double buffer
    shortx8 bQ0[2][2], bQ1[2][2], bR0[2][2];  // B halves (bQ1 = tile1 B1 too)

#define LDSV(off) (*(const shortx8*)(lds + (off)))
#define READ_A(dst, g, bo) do {                                             \
    const int ab_ = (bo) + (g) * 16384;                                     \
    dst[0][0] = LDSV(ab_ + a_b0);        dst[0][1] = LDSV(ab_ + a_b1);      \
    dst[1][0] = LDSV(ab_ + a_b0 + 2048); dst[1][1] = LDSV(ab_ + a_b1 + 2048);\
    dst[2][0] = LDSV(ab_ + a_b0 + 4096); dst[2][1] = LDSV(ab_ + a_b1 + 4096);\
    dst[3][0] = LDSV(ab_ + a_b0 + 6144); dst[3][1] = LDSV(ab_ + a_b1 + 6144);\
} while (0)
#define READ_B(dst, g, bo) do {                                             \
    const int bb_ = (bo) + 32768 + (g) * 16384;                             \
    dst[0][0] = LDSV(bb_ + b_b0);        dst[0][1] = LDSV(bb_ + b_b1);      \
    dst[1][0] = LDSV(bb_ + b_b0 + 2048); dst[1][1] = LDSV(bb_ + b_b1 + 2048);\
} while (0)
#define STAGE(xs, h, buf, kofs) do {                                        \
    char* d_ = lds + (buf) * 65536 + (xs) * 32768 + (h) * 16384 + wave * 1024; \
    load_lds16(((xs) ? srcB : srcA)[h][0] + (kofs), (__hip_bfloat16*)d_);   \
    load_lds16(((xs) ? srcB : srcA)[h][1] + (kofs), (__hip_bfloat16*)(d_ + 8192)); \
} while (0)
#define MFQ(mh, nh, AF, BF) do {                                            \
    __builtin_amdgcn_s_setprio(1);                                          \
    _Pragma("unroll")                                                       \
    for (int ii_ = 0; ii_ < 4; ii_++)                                       \
        _Pragma("unroll")                                                   \
        for (int jj_ = 0; jj_ < 2; jj_++) {                                 \
            acc[(mh)*4+ii_][(nh)*2+jj_] = __builtin_amdgcn_mfma_f32_16x16x32_bf16( \
                AF[ii_][0], BF[jj_][0], acc[(mh)*4+ii_][(nh)*2+jj_], 0, 0, 0); \
            acc[(mh)*4+ii_][(nh)*2+jj_] = __builtin_amdgcn_mfma_f32_16x16x32_bf16( \
                AF[ii_][1], BF[jj_][1], acc[(mh)*4+ii_][(nh)*2+jj_], 0, 0, 0); \
        }                                                                   \
    __builtin_amdgcn_s_setprio(0);                                          \
} while (0)
#define BAR() __builtin_amdgcn_s_barrier()
#define LGKM0()  asm volatile("s_waitcnt lgkmcnt(0)" ::: "memory")
#define LGKM4()  asm volatile("s_waitcnt lgkmcnt(4)" ::: "memory")
#define LGKM8()  asm volatile("s_waitcnt lgkmcnt(8)" ::: "memory")
#define LGKM12() asm volatile("s_waitcnt lgkmcnt(12)" ::: "memory")
#define VMC6() asm volatile("s_waitcnt vmcnt(6)" ::: "memory")
#define VMC0() asm volatile("s_waitcnt vmcnt(0)" ::: "memory")

    // ---- prologue: stage buf0 fully + buf1.{A0,B1,A1}; order matches
    // steady-state issue order so vmcnt counting lines up ----
    STAGE(0, 0, 0, kb);        // buf0.A0
    STAGE(1, 1, 0, kb);        // buf0.B1
    STAGE(0, 1, 0, kb);        // buf0.A1
    STAGE(1, 0, 0, kb);        // buf0.B0
    STAGE(0, 0, 1, kb + 64);   // buf1.A0
    STAGE(1, 1, 1, kb + 64);   // buf1.B1
    STAGE(0, 1, 1, kb + 64);   // buf1.A1
    VMC6();                    // buf0 landed, 3 halves in flight
    BAR();
    // pre-read ph1 operands (A0,B0 of buf0)
    READ_A(afX, 0, 0); READ_B(bQ0, 0, 0);

#define ITER(E, kcur, knext) do {                                           \
    /* ph1: issue B1b0 (for ph2); MFQ uses afX/bQ0 (prologue/ph8 reads) */  \
    READ_B(bQ1, 1, 0); STAGE(1, 0, 1, (kcur) + 64);                         \
    BAR(); LGKM4(); MFQ(0, 0, afX, bQ0); BAR();                             \
    /* ph2: issue A1b0 (for ph3) */                                         \
    READ_A(afY, 1, 0); if (E) STAGE(0, 0, 0, (knext));                      \
    BAR(); LGKM8(); MFQ(0, 1, afX, bQ1); BAR();                             \
    /* ph3: no reads */                                                     \
    if (E) STAGE(1, 1, 0, (knext));                                         \
    BAR(); LGKM0(); MFQ(1, 1, afY, bQ1); BAR();                             \
    /* ph4: vmcnt+bar FIRST (buf1.B0 landing), then 12-read burst for ph5   \
       overlapping this phase's MFMA */                                     \
    if (E) { STAGE(0, 1, 0, (knext)); VMC6(); } else { VMC0(); }            \
    BAR(); READ_A(afX, 0, 65536); READ_B(bR0, 0, 65536); LGKM12();          \
    MFQ(1, 0, afY, bQ0); BAR();                                             \
    /* ph5: issue B1b1 (for ph6) */                                         \
    READ_B(bQ1, 1, 65536); if (E) STAGE(1, 0, 0, (knext));                  \
    BAR(); LGKM4(); MFQ(0, 0, afX, bR0); BAR();                             \
    /* ph6: issue A1b1 (for ph7) */                                         \
    READ_A(afY, 1, 65536); if (E) STAGE(0, 0, 1, (knext) + 64);             \
    BAR(); LGKM8(); MFQ(0, 1, afX, bQ1); BAR();                             \
    /* ph7: no reads */                                                     \
    if (E) STAGE(1, 1, 1, (knext) + 64);                                    \
    BAR(); LGKM0(); MFQ(1, 1, afY, bQ1); BAR();                             \
    /* ph8: vmcnt+bar then 12-read burst for next ph1 (A0',B0' of buf0) */  \
    if (E) { STAGE(0, 1, 1, (knext) + 64); VMC6(); }                        \
    BAR();                                                                  \
    if (E) { READ_A(afX, 0, 0); READ_B(bQ0, 0, 0); LGKM12(); }              \
    else   { LGKM0(); }                                                     \
    MFQ(1, 0, afY, bR0); BAR();                                             \
} while (0)

    int it = 0;
    #pragma unroll 1
    for (; it < niters - 1; ++it) {
        const int kc = kb + it * 128;
        ITER(1, kc, kc + 128);
    }
    {   // last iteration: no next-tile staging, full drain at ph4
        const int kc = kb + it * 128;
        ITER(0, kc, 0);
    }

#undef ITER
#undef LDSV
#undef READ_A
#undef READ_B
#undef STAGE
#undef MFQ
#undef BAR
#undef LGKM0
#undef LGKM4
#undef LGKM8
#undef LGKM12
#undef VMC6
#undef VMC0

    // ---- epilogue (round-1 verified direct stores) ----
    // row = bm*256 + wm*128 + (i>>2)*64 + (i&3)*16 + lq*4 + r
    // col = bn*256 + (wn>>1)*128 + (j>>1)*64 + (wn&1)*32 + (j&1)*16 + lm
    if (EPI == 2) {
        #pragma unroll
        for (int i = 0; i < 8; i++) {
            const int grow0 = bm * 256 + wm * 128 + (i >> 2) * 64 + (i & 3) * 16 + lq * 4;
            #pragma unroll
            for (int r = 0; r < 4; r++) {
                float rs = 0.f;
                #pragma unroll
                for (int j = 0; j < 4; j++) {
                    const int gcol = bn * 256 + (wn >> 1) * 128 + (j >> 1) * 64 +
                                     (wn & 1) * 32 + (j & 1) * 16 + lm;
                    float e = __expf(acc[i][j][r] * scale);
                    unsigned short eb = f2b_bits(e);
                    ((unsigned short*)outH)[(size_t)(grow0 + r) * N + gcol] = eb;
                    rs += b2f_bits(eb);
                }
                rs += __shfl_xor(rs, 1, 64);
                rs += __shfl_xor(rs, 2, 64);
                rs += __shfl_xor(rs, 4, 64);
                rs += __shfl_xor(rs, 8, 64);
                if (lm == 0)
                    ps[(size_t)(grow0 + r) * PS_COLS + bn * 4 + wn] = rs;
            }
        }
    } else {
        __hip_bfloat16* outHz = outH + ((EPI == 4) ? (size_t)blockIdx.z * M * N : 0);
        #pragma unroll
        for (int i = 0; i < 8; i++) {
            const int grow0 = bm * 256 + wm * 128 + (i >> 2) * 64 + (i & 3) * 16 + lq * 4;
            #pragma unroll
            for (int j = 0; j < 4; j++) {
                const int gcol = bn * 256 + (wn >> 1) * 128 + (j >> 1) * 64 +
                                 (wn & 1) * 32 + (j & 1) * 16 + lm;
                #pragma unroll
                for (int r = 0; r < 4; r++) {
                    float v = acc[i][j][r];
                    size_t idx = (size_t)(grow0 + r) * N + gcol;
                    if (EPI == 1) outHz[idx] = __float2bfloat16(v + biasSel[gcol]);
                    else          outHz[idx] = __float2bfloat16(v * scale);
                }
            }
        }
    }
}

// ------- final: out[row] = (sum of bf16 partials) / (sum of ps[row][*]) -------
__global__ __launch_bounds__(256) void reduce4_k(const ushortx4* __restrict__ part,
                                                 const float* __restrict__ ps,
                                                 float4* __restrict__ out) {
    int row = blockIdx.x;
    float s = 0.f;
    if (threadIdx.x < PS_COLS) s = ps[(size_t)row * PS_COLS + threadIdx.x];
    float tot = blockReduceSum(s);
    float inv = 1.f / tot;
    size_t base = (size_t)row * (HDIM / 4) + threadIdx.x;
    const size_t stride = (size_t)BS_CAND * (HDIM / 4);
    float4 o = {0.f, 0.f, 0.f, 0.f};
    #pragma unroll
    for (int z = 0; z < PV_SPLIT; z++) {
        ushortx4 p = part[base + (size_t)z * stride];
        o.x += b2f_bits(p.x); o.y += b2f_bits(p.y);
        o.z += b2f_bits(p.z); o.w += b2f_bits(p.w);
    }
    o.x *= inv; o.y *= inv; o.z *= inv; o.w *= inv;
    out[(size_t)row * (HDIM / 4) + threadIdx.x] = o;
}

// ---------------- launch ----------------
extern "C" void kernel_launch(void* const* d_in, const int* in_sizes, int n_in,
                              void* d_out, int out_size, void* d_ws, size_t ws_size,
                              hipStream_t stream) {
    const float* hidden = (const float*)d_in[0];   // [2,2048,1024]
    const float* membuf = (const float*)d_in[1];   // [8192,1024]
    const float* imp    = (const float*)d_in[2];   // [8192]
    const float* Wq     = (const float*)d_in[3];   // [1024,1024]
    const float* bq     = (const float*)d_in[4];   // [1024]
    const float* Wk     = (const float*)d_in[5];   // [1024,1024]
    const float* bk     = (const float*)d_in[6];   // [1024]
    const float* noise  = (const float*)d_in[7];   // [8192]

    // 128 KiB dynamic LDS needs the opt-in attribute (once per process)
    static bool s_attr = false;
    if (!s_attr) {
        (void)hipFuncSetAttribute((const void*)gemm_bt<1, 0>,
                                  hipFuncAttributeMaxDynamicSharedMemorySize, 131072);
        (void)hipFuncSetAttribute((const void*)gemm_bt<2, 0>,
                                  hipFuncAttributeMaxDynamicSharedMemorySize, 131072);
        (void)hipFuncSetAttribute((const void*)gemm_bt<4, 1>,
                                  hipFuncAttributeMaxDynamicSharedMemorySize, 131072);
        s_attr = true;
    }

    char* ws = (char*)d_ws;
    size_t off = 0;
    auto alloc = [&](size_t bytes) -> void* {
        void* p = ws + off;
        off += (bytes + 255) & ~(size_t)255;
        return p;
    };
    // --- persistent region (front) ---
    float*          surprise = (float*)alloc(BS_CAND * 4);
    float*          skeys    = (float*)alloc(MSLOTS * 4);
    float*          ps       = (float*)alloc((size_t)BS_CAND * PS_COLS * 4);   // 2 MB
    int*            cand_ord = (int*)alloc(BS_CAND * 4);
    int*            slot_ord = (int*)alloc(MSLOTS * 4);
    int*            row_src  = (int*)alloc(MSLOTS * 4);
    __hip_bfloat16* Wqbf = (__hip_bfloat16*)alloc((size_t)HDIM * HDIM * 2);    // 2 MB
    __hip_bfloat16* Wkbf = (__hip_bfloat16*)alloc((size_t)HDIM * HDIM * 2);    // 2 MB
    __hip_bfloat16* BbfT = (__hip_bfloat16*)alloc((size_t)HDIM * MSLOTS * 2);  // 16 MB
    // --- Sbf region (64 MB), overlaid with Hbf (8 MB) + Bbf (16 MB), which are
    // CONTIGUOUS (A = [H; B] for the fused projection GEMM) and die before the
    // scores GEMM writes Sbf ---
    size_t s_base = off;
    __hip_bfloat16* Sbf = (__hip_bfloat16*)(ws + s_base);                      // 64 MB
    __hip_bfloat16* Hbf = (__hip_bfloat16*)(ws + s_base);                      //  8 MB
    __hip_bfloat16* Bbf = (__hip_bfloat16*)(ws + s_base + (size_t)BS_CAND * HDIM * 2);
    off = s_base + ((size_t)BS_CAND * MSLOTS * 2 + 255) & ~(size_t)255;
    // --- tail region: qbf+mkbf CONTIGUOUS; PV partials overlay them later ---
    size_t t_base = off;
    __hip_bfloat16* qbf  = (__hip_bfloat16*)alloc((size_t)BS_CAND * HDIM * 2); // 8 MB
    __hip_bfloat16* mkbf = (__hip_bfloat16*)alloc((size_t)MSLOTS * HDIM * 2);  // 16 MB
    __hip_bfloat16* part = (__hip_bfloat16*)(ws + t_base);  // 4 x 8 MB bf16 partials

    // 1) merged prologue: hidden norm+cast | slot keys | Wq/Wk cast
    pre_k<<<BS_CAND + MSLOTS / 256 + 2048, 256, 0, stream>>>(
        hidden, surprise, Hbf, imp, noise, skeys, row_src, Wq, Wqbf, Wk, Wkbf);
    // 2) both rankings in one launch
    ranks_k<<<BS_CAND + MSLOTS, 256, 0, stream>>>(surprise, cand_ord, skeys, slot_ord);
    scatter_k<<<BS_CAND / 256, 256, 0, stream>>>(cand_ord, slot_ord, surprise, row_src);
    // 3) updated memory buffer + its transpose, fused one-pass
    bbt_k<<<dim3(HDIM / 64, MSLOTS / 64), 256, 0, stream>>>(
        membuf, hidden, row_src, Bbf, BbfT);
    // 4) fused projections: [q; mk] = [H; newbuf] @ {Wq,Wk}^T + {bq,bk}
    gemm_bt<1, 0><<<dim3(HDIM / 256, (BS_CAND + MSLOTS) / 256), 512, 131072, stream>>>(
        Hbf, Wqbf, Wkbf, qbf, bq, bk, nullptr, BS_CAND / 256,
        BS_CAND + MSLOTS, HDIM, HDIM, HDIM, 1.f);
    // 5) E = bf16(exp((q @ mk^T)/32)) + per-wave strip sums into ps
    gemm_bt<2, 0><<<dim3(MSLOTS / 256, BS_CAND / 256), 512, 131072, stream>>>(
        qbf, mkbf, nullptr, Sbf, nullptr, nullptr, ps, 1 << 30,
        BS_CAND, MSLOTS, HDIM, HDIM, 0.03125f);
    // 6) split-K PV: bf16 partial[z] = E @ newbuf over K-chunk z
    gemm_bt<4, 1><<<dim3(BS_CAND / 256, HDIM / 256, PV_SPLIT), 512, 131072, stream>>>(
        Sbf, BbfT, nullptr, part, nullptr, nullptr, nullptr, 1 << 30,
        BS_CAND, HDIM, MSLOTS, MSLOTS / PV_SPLIT, 1.f);
    // 7) out = (sum of 4 bf16 partials) / rowsum(ps)   -> fp32 [4096,1024]
    reduce4_k<<<BS_CAND, 256, 0, stream>>>((const ushortx4*)part, ps, (float4*)d_out);
}

// Round 6
// 315.126 us; speedup vs baseline: 2.0615x; 2.0615x over previous
//
#include <hip/hip_runtime.h>
#include <hip/hip_bf16.h>
#include <math.h>
#include <stdint.h>

typedef __attribute__((ext_vector_type(4))) float floatx4;
typedef __attribute__((ext_vector_type(8))) short shortx8;
typedef __attribute__((ext_vector_type(4))) unsigned short ushortx4;

#define BS_CAND 4096   // B*S
#define HDIM    1024
#define MSLOTS  8192
#define THRESH  64.0f
#define PV_SPLIT 4
#define PS_COLS 128    // 32 bn-tiles x 4 n-waves

__device__ __forceinline__ unsigned short f2b_bits(float f) {
    __hip_bfloat16 b = __float2bfloat16(f);
    return *(unsigned short*)&b;
}
__device__ __forceinline__ float b2f_bits(unsigned short u) {
    return __uint_as_float(((unsigned)u) << 16);
}

// ---------------- reduction helper (blockDim == 256) ----------------
__device__ __forceinline__ float blockReduceSum(float x) {
    __shared__ float red[4];
    #pragma unroll
    for (int o = 32; o > 0; o >>= 1) x += __shfl_down(x, o, 64);
    int lane = threadIdx.x & 63, w = threadIdx.x >> 6;
    if (lane == 0) red[w] = x;
    __syncthreads();
    float s = red[0] + red[1] + red[2] + red[3];
    __syncthreads();
    return s;
}

// ------- merged prologue: norm+cast of hidden | slot keys | Wq/Wk cast -------
__global__ __launch_bounds__(256) void pre_k(const float* __restrict__ h,
                                             float* __restrict__ sur,
                                             __hip_bfloat16* __restrict__ Hbf,
                                             const float* __restrict__ imp,
                                             const float* __restrict__ noi,
                                             float* __restrict__ keys,
                                             int* __restrict__ row_src,
                                             const float* __restrict__ Wq,
                                             __hip_bfloat16* __restrict__ Wqbf,
                                             const float* __restrict__ Wk,
                                             __hip_bfloat16* __restrict__ Wkbf) {
    int b = blockIdx.x;
    if (b < BS_CAND) {
        float4 v = ((const float4*)(h + (size_t)b * HDIM))[threadIdx.x];
        ushortx4 o;
        o.x = f2b_bits(v.x); o.y = f2b_bits(v.y);
        o.z = f2b_bits(v.z); o.w = f2b_bits(v.w);
        ((ushortx4*)(Hbf + (size_t)b * HDIM))[threadIdx.x] = o;
        float s = v.x * v.x + v.y * v.y + v.z * v.z + v.w * v.w;
        float tot = blockReduceSum(s);
        if (threadIdx.x == 0) sur[b] = 2.0f * sqrtf(tot);
    } else if (b < BS_CAND + MSLOTS / 256) {
        int i = (b - BS_CAND) * 256 + threadIdx.x;
        keys[i] = imp[i] + noi[i] * 1e-6f;
        row_src[i] = -1;
    } else {
        int w = b - (BS_CAND + MSLOTS / 256);          // 0..2047
        const float* in = (w < 1024) ? Wq : Wk;
        __hip_bfloat16* out = (w < 1024) ? Wqbf : Wkbf;
        int j = (w & 1023) * 256 + threadIdx.x;        // float4 index
        float4 v = ((const float4*)in)[j];
        ushortx4 o;
        o.x = f2b_bits(v.x); o.y = f2b_bits(v.y);
        o.z = f2b_bits(v.z); o.w = f2b_bits(v.w);
        ((ushortx4*)out)[j] = o;
    }
}

// ---------------- merged ranks: one BLOCK per element ----------------
__global__ __launch_bounds__(256) void ranks_k(const float* __restrict__ sur,
                                               int* __restrict__ cand_ord,
                                               const float* __restrict__ keys,
                                               int* __restrict__ slot_ord) {
    int b = blockIdx.x;
    if (b < BS_CAND) {
        float ki = sur[b];
        float cnt = 0.f;
        for (int j = threadIdx.x; j < BS_CAND; j += 256) {
            float kj = sur[j];
            cnt += ((kj > ki) || (kj == ki && j < b)) ? 1.f : 0.f;
        }
        float r = blockReduceSum(cnt);
        if (threadIdx.x == 0) cand_ord[(int)r] = b;
    } else {
        int i = b - BS_CAND;
        float ki = keys[i];
        float cnt = 0.f;
        for (int j = threadIdx.x; j < MSLOTS; j += 256) {
            float kj = keys[j];
            cnt += ((kj < ki) || (kj == ki && j < i)) ? 1.f : 0.f;
        }
        float r = blockReduceSum(cnt);
        if (threadIdx.x == 0) slot_ord[(int)r] = i;
    }
}

// ---------------- scatter: rank-i candidate -> rank-i least-important slot ----
__global__ __launch_bounds__(256) void scatter_k(const int* __restrict__ cand_order,
                                                 const int* __restrict__ slot_order,
                                                 const float* __restrict__ sur,
                                                 int* __restrict__ row_src) {
    int i = blockIdx.x * 256 + threadIdx.x;   // i < BS_CAND
    int c = cand_order[i];
    if (sur[c] > THRESH) row_src[slot_order[i]] = c;
}

// ------ merged build+transpose: Bbf row-major AND BbfT, one pass ------
__global__ __launch_bounds__(256) void bbt_k(const float* __restrict__ mem,
                                             const float* __restrict__ hid,
                                             const int* __restrict__ src,
                                             __hip_bfloat16* __restrict__ B,
                                             __hip_bfloat16* __restrict__ BT) {
    __shared__ unsigned short t[64][72];
    int cb = blockIdx.x * 64, rb = blockIdx.y * 64;
    int tx = threadIdx.x & 63, ty = threadIdx.x >> 6;
    #pragma unroll
    for (int k = 0; k < 16; k++) {
        int r = ty * 16 + k;
        int s = src[rb + r];
        const float* row = (s < 0) ? (mem + (size_t)(rb + r) * HDIM)
                                   : (hid + (size_t)s * HDIM);
        unsigned short b = f2b_bits(row[cb + tx]);
        t[r][tx] = b;
        ((unsigned short*)B)[(size_t)(rb + r) * HDIM + cb + tx] = b;
    }
    __syncthreads();
    #pragma unroll
    for (int k = 0; k < 16; k++) {
        int c = ty * 16 + k;
        ((unsigned short*)BT)[(size_t)(cb + c) * MSLOTS + rb + tx] = t[tx][c];
    }
}

// ---------------- async global->LDS helper ----------------
__device__ __forceinline__ void load_lds16(const __hip_bfloat16* g, __hip_bfloat16* l) {
    __builtin_amdgcn_global_load_lds(
        (const __attribute__((address_space(1))) void*)g,
        (__attribute__((address_space(3))) void*)l, 16, 0, 0);
}

// =====================================================================
// 256x256 4-PHASE BT-GEMM (T2+T4+T5; barrier-halved vs r1/r4 8-phase):
// same LDS layout / swizzle / B-hold / register budget as R4 (no new
// register sets -> no spill: R5's lesson). Per iter (2 K-tiles, 128 K):
//   P1: read b0{A-h0,B-h0,B-h1} (16), stage h=b1.A1@kc+64;    32 MFMA
//   P2: read b0{A-h1} (8), stage i=b0.A0',j=b0.B0'; VMC4;     32 MFMA
//   P3: read b1{A-h0,B-h0,B-h1} (16), stage k=b0.B1',l=b0.A1';32 MFMA
//   P4: read b1{A-h1} (8), stage m=b1.A0'',n=b1.B0'',o=b1.B1''; VMC6; 32
// vmcnt proof (2 loads/stage, issue order ...,m,n,o,h,i,j,k,l,m',...):
//   P4-end outstanding {i,j,k,l,m,n,o}=14; VMC6 drains i..l -> all b0'
//   landed for next P1/P2; remaining {m,n,o}=6.
//   P2-end outstanding {m,n,o,h,i,j}=12; VMC4 drains m,n,o,h -> all b1
//   landed for P3/P4; remaining {i,j}=4.
// WAR: every STAGE region's last ds_read drained by the LGKM0 of its
// phase, >=1 barrier before the stage (checked per region).
// Last iter (E=0): P1 still stages h (read this P4); P2 VMC0 drains all.
// EPI 1/2/4 unchanged (r1-verified).
// =====================================================================
template <int EPI, int SWAP>
__global__ __launch_bounds__(512, 2) void gemm_bt(const __hip_bfloat16* __restrict__ A,
                                                  const __hip_bfloat16* __restrict__ Bt,
                                                  const __hip_bfloat16* __restrict__ Bt2,
                                                  __hip_bfloat16* __restrict__ outH,
                                                  const float* __restrict__ bias,
                                                  const float* __restrict__ bias2,
                                                  float* __restrict__ ps,
                                                  int rows0b,
                                                  int M, int N, int K, int ksplit,
                                                  float scale) {
    extern __shared__ char lds[];
    const int tid = threadIdx.x;
    const int wave = tid >> 6, lane = tid & 63;
    const int lm = lane & 15, lq = lane >> 4;
    const int wm = wave >> 2, wn = wave & 3;
    const int bm = SWAP ? blockIdx.x : blockIdx.y;
    const int bn = SWAP ? blockIdx.y : blockIdx.x;
    const int kb = blockIdx.z * ksplit;
    const int niters = ksplit >> 7;            // 128 of K per iteration

    const __hip_bfloat16* BtSel = (EPI == 1 && bm >= rows0b) ? Bt2 : Bt;
    const float* biasSel = (EPI == 1 && bm >= rows0b) ? bias2 : bias;

    // ---- per-thread staging source pointers (pre-swizzled global src) ----
    const int l8 = lane >> 3;
    const int colsrc = ((((lane & 7) << 4) ^ (l8 << 4)) >> 1);
    const __hip_bfloat16* Abase = A + (size_t)bm * 256 * K;
    const __hip_bfloat16* Bbase = BtSel + (size_t)bn * 256 * K;
    const __hip_bfloat16* srcA[2][2];
    const __hip_bfloat16* srcB[2][2];
    #pragma unroll
    for (int h = 0; h < 2; h++)
        #pragma unroll
        for (int t = 0; t < 2; t++) {
            int row = t * 128 + h * 64 + wave * 8 + l8;
            srcA[h][t] = Abase + (size_t)row * K + colsrc;
            srcB[h][t] = Bbase + (size_t)row * K + colsrc;
        }

    // ---- ds_read fragment byte offsets (swizzled) ----
    const int cxor = (lq << 4) ^ ((lm & 7) << 4);
    const int a_b0 = (wm * 64 + lm) * 128 + cxor;
    const int a_b1 = a_b0 ^ 64;
    const int b_b0 = (wn * 32 + lm) * 128 + cxor;
    const int b_b1 = b_b0 ^ 64;

    floatx4 acc[8][4];
    #pragma unroll
    for (int i = 0; i < 8; i++)
        #pragma unroll
        for (int j = 0; j < 4; j++) acc[i][j] = {0.f, 0.f, 0.f, 0.f};

    shortx8 af[4][2], bf0h[2][2], bf1h[2][2];

#define LDSV(off) (*(const shortx8*)(lds + (off)))
#define READ_A(g, bo) do {                                                  \
    const int ab_ = (bo) + (g) * 16384;                                     \
    af[0][0] = LDSV(ab_ + a_b0);        af[0][1] = LDSV(ab_ + a_b1);        \
    af[1][0] = LDSV(ab_ + a_b0 + 2048); af[1][1] = LDSV(ab_ + a_b1 + 2048); \
    af[2][0] = LDSV(ab_ + a_b0 + 4096); af[2][1] = LDSV(ab_ + a_b1 + 4096); \
    af[3][0] = LDSV(ab_ + a_b0 + 6144); af[3][1] = LDSV(ab_ + a_b1 + 6144); \
} while (0)
#define READ_B(dst, g, bo) do {                                             \
    const int bb_ = (bo) + 32768 + (g) * 16384;                             \
    dst[0][0] = LDSV(bb_ + b_b0);        dst[0][1] = LDSV(bb_ + b_b1);      \
    dst[1][0] = LDSV(bb_ + b_b0 + 2048); dst[1][1] = LDSV(bb_ + b_b1 + 2048);\
} while (0)
#define STAGE(xs, h, buf, kofs) do {                                        \
    char* d_ = lds + (buf) * 65536 + (xs) * 32768 + (h) * 16384 + wave * 1024; \
    load_lds16(((xs) ? srcB : srcA)[h][0] + (kofs), (__hip_bfloat16*)d_);   \
    load_lds16(((xs) ? srcB : srcA)[h][1] + (kofs), (__hip_bfloat16*)(d_ + 8192)); \
} while (0)
#define MFQ(mh, nh, BF) do {                                                \
    __builtin_amdgcn_s_setprio(1);                                          \
    _Pragma("unroll")                                                       \
    for (int ii_ = 0; ii_ < 4; ii_++)                                       \
        _Pragma("unroll")                                                   \
        for (int jj_ = 0; jj_ < 2; jj_++) {                                 \
            acc[(mh)*4+ii_][(nh)*2+jj_] = __builtin_amdgcn_mfma_f32_16x16x32_bf16( \
                af[ii_][0], BF[jj_][0], acc[(mh)*4+ii_][(nh)*2+jj_], 0, 0, 0); \
            acc[(mh)*4+ii_][(nh)*2+jj_] = __builtin_amdgcn_mfma_f32_16x16x32_bf16( \
                af[ii_][1], BF[jj_][1], acc[(mh)*4+ii_][(nh)*2+jj_], 0, 0, 0); \
        }                                                                   \
    __builtin_amdgcn_s_setprio(0);                                          \
} while (0)
#define BAR() __builtin_amdgcn_s_barrier()
#define LGKM0() asm volatile("s_waitcnt lgkmcnt(0)" ::: "memory")
#define VMC6() asm volatile("s_waitcnt vmcnt(6)" ::: "memory")
#define VMC4() asm volatile("s_waitcnt vmcnt(4)" ::: "memory")
#define VMC0() asm volatile("s_waitcnt vmcnt(0)" ::: "memory")

    // ---- prologue: b0 full (A0,B0,B1,A1) + b1 (A0,B0,B1); VMC6 -> b0
    // landed, {b1.A0,B0,B1}=6 loads in flight (steady-state {m,n,o}) ----
    STAGE(0, 0, 0, kb);        // b0.A0
    STAGE(1, 0, 0, kb);        // b0.B0
    STAGE(1, 1, 0, kb);        // b0.B1
    STAGE(0, 1, 0, kb);        // b0.A1
    STAGE(0, 0, 1, kb + 64);   // b1.A0   (m)
    STAGE(1, 0, 1, kb + 64);   // b1.B0   (n)
    STAGE(1, 1, 1, kb + 64);   // b1.B1   (o)
    VMC6();
    BAR();

#define ITER(E, kcur, knext) do {                                           \
    /* P1: b0 reads A-h0,B0,B1; stage h=b1.A1@kcur+64 */                    \
    READ_A(0, 0); READ_B(bf0h, 0, 0); READ_B(bf1h, 1, 0);                   \
    STAGE(0, 1, 1, (kcur) + 64);                                            \
    BAR(); LGKM0(); MFQ(0, 0, bf0h); MFQ(0, 1, bf1h); BAR();                \
    /* P2: b0 read A-h1; stage i=b0.A0',j=b0.B0'; VMC4 drains b1 set */     \
    READ_A(1, 0);                                                           \
    if (E) { STAGE(0, 0, 0, (knext)); STAGE(1, 0, 0, (knext)); VMC4(); }    \
    else   { VMC0(); }                                                      \
    BAR(); LGKM0(); MFQ(1, 1, bf1h); MFQ(1, 0, bf0h); BAR();                \
    /* P3: b1 reads A-h0,B0,B1; stage k=b0.B1',l=b0.A1' */                  \
    READ_A(0, 65536); READ_B(bf0h, 0, 65536); READ_B(bf1h, 1, 65536);       \
    if (E) { STAGE(1, 1, 0, (knext)); STAGE(0, 1, 0, (knext)); }            \
    BAR(); LGKM0(); MFQ(0, 0, bf0h); MFQ(0, 1, bf1h); BAR();                \
    /* P4: b1 read A-h1; stage m,n,o = b1.{A0,B0,B1}''; VMC6 drains b0' */  \
    READ_A(1, 65536);                                                       \
    if (E) { STAGE(0, 0, 1, (knext) + 64); STAGE(1, 0, 1, (knext) + 64);    \
             STAGE(1, 1, 1, (knext) + 64); VMC6(); }                        \
    BAR(); LGKM0(); MFQ(1, 1, bf1h); MFQ(1, 0, bf0h); BAR();                \
} while (0)

    int it = 0;
    #pragma unroll 1
    for (; it < niters - 1; ++it) {
        const int kc = kb + it * 128;
        ITER(1, kc, kc + 128);
    }
    {   // last iteration: only P1's b1.A1 stage; P2 drains everything
        const int kc = kb + it * 128;
        ITER(0, kc, 0);
    }

#undef ITER
#undef LDSV
#undef READ_A
#undef READ_B
#undef STAGE
#undef MFQ
#undef BAR
#undef LGKM0
#undef VMC6
#undef VMC4
#undef VMC0

    // ---- epilogue (round-1 verified direct stores) ----
    // row = bm*256 + wm*128 + (i>>2)*64 + (i&3)*16 + lq*4 + r
    // col = bn*256 + (wn>>1)*128 + (j>>1)*64 + (wn&1)*32 + (j&1)*16 + lm
    if (EPI == 2) {
        #pragma unroll
        for (int i = 0; i < 8; i++) {
            const int grow0 = bm * 256 + wm * 128 + (i >> 2) * 64 + (i & 3) * 16 + lq * 4;
            #pragma unroll
            for (int r = 0; r < 4; r++) {
                float rs = 0.f;
                #pragma unroll
                for (int j = 0; j < 4; j++) {
                    const int gcol = bn * 256 + (wn >> 1) * 128 + (j >> 1) * 64 +
                                     (wn & 1) * 32 + (j & 1) * 16 + lm;
                    float e = __expf(acc[i][j][r] * scale);
                    unsigned short eb = f2b_bits(e);
                    ((unsigned short*)outH)[(size_t)(grow0 + r) * N + gcol] = eb;
                    rs += b2f_bits(eb);
                }
                rs += __shfl_xor(rs, 1, 64);
                rs += __shfl_xor(rs, 2, 64);
                rs += __shfl_xor(rs, 4, 64);
                rs += __shfl_xor(rs, 8, 64);
                if (lm == 0)
                    ps[(size_t)(grow0 + r) * PS_COLS + bn * 4 + wn] = rs;
            }
        }
    } else {
        __hip_bfloat16* outHz = outH + ((EPI == 4) ? (size_t)blockIdx.z * M * N : 0);
        #pragma unroll
        for (int i = 0; i < 8; i++) {
            const int grow0 = bm * 256 + wm * 128 + (i >> 2) * 64 + (i & 3) * 16 + lq * 4;
            #pragma unroll
            for (int j = 0; j < 4; j++) {
                const int gcol = bn * 256 + (wn >> 1) * 128 + (j >> 1) * 64 +
                                 (wn & 1) * 32 + (j & 1) * 16 + lm;
                #pragma unroll
                for (int r = 0; r < 4; r++) {
                    float v = acc[i][j][r];
                    size_t idx = (size_t)(grow0 + r) * N + gcol;
                    if (EPI == 1) outHz[idx] = __float2bfloat16(v + biasSel[gcol]);
                    else          outHz[idx] = __float2bfloat16(v * scale);
                }
            }
        }
    }
}

// ------- final: out[row] = (sum of bf16 partials) / (sum of ps[row][*]) -------
__global__ __launch_bounds__(256) void reduce4_k(const ushortx4* __restrict__ part,
                                                 const float* __restrict__ ps,
                                                 float4* __restrict__ out) {
    int row = blockIdx.x;
    float s = 0.f;
    if (threadIdx.x < PS_COLS) s = ps[(size_t)row * PS_COLS + threadIdx.x];
    float tot = blockReduceSum(s);
    float inv = 1.f / tot;
    size_t base = (size_t)row * (HDIM / 4) + threadIdx.x;
    const size_t stride = (size_t)BS_CAND * (HDIM / 4);
    float4 o = {0.f, 0.f, 0.f, 0.f};
    #pragma unroll
    for (int z = 0; z < PV_SPLIT; z++) {
        ushortx4 p = part[base + (size_t)z * stride];
        o.x += b2f_bits(p.x); o.y += b2f_bits(p.y);
        o.z += b2f_bits(p.z); o.w += b2f_bits(p.w);
    }
    o.x *= inv; o.y *= inv; o.z *= inv; o.w *= inv;
    out[(size_t)row * (HDIM / 4) + threadIdx.x] = o;
}

// ---------------- launch ----------------
extern "C" void kernel_launch(void* const* d_in, const int* in_sizes, int n_in,
                              void* d_out, int out_size, void* d_ws, size_t ws_size,
                              hipStream_t stream) {
    const float* hidden = (const float*)d_in[0];   // [2,2048,1024]
    const float* membuf = (const float*)d_in[1];   // [8192,1024]
    const float* imp    = (const float*)d_in[2];   // [8192]
    const float* Wq     = (const float*)d_in[3];   // [1024,1024]
    const float* bq     = (const float*)d_in[4];   // [1024]
    const float* Wk     = (const float*)d_in[5];   // [1024,1024]
    const float* bk     = (const float*)d_in[6];   // [1024]
    const float* noise  = (const float*)d_in[7];   // [8192]

    // 128 KiB dynamic LDS needs the opt-in attribute (once per process)
    static bool s_attr = false;
    if (!s_attr) {
        (void)hipFuncSetAttribute((const void*)gemm_bt<1, 0>,
                                  hipFuncAttributeMaxDynamicSharedMemorySize, 131072);
        (void)hipFuncSetAttribute((const void*)gemm_bt<2, 0>,
                                  hipFuncAttributeMaxDynamicSharedMemorySize, 131072);
        (void)hipFuncSetAttribute((const void*)gemm_bt<4, 1>,
                                  hipFuncAttributeMaxDynamicSharedMemorySize, 131072);
        s_attr = true;
    }

    char* ws = (char*)d_ws;
    size_t off = 0;
    auto alloc = [&](size_t bytes) -> void* {
        void* p = ws + off;
        off += (bytes + 255) & ~(size_t)255;
        return p;
    };
    // --- persistent region (front) ---
    float*          surprise = (float*)alloc(BS_CAND * 4);
    float*          skeys    = (float*)alloc(MSLOTS * 4);
    float*          ps       = (float*)alloc((size_t)BS_CAND * PS_COLS * 4);   // 2 MB
    int*            cand_ord = (int*)alloc(BS_CAND * 4);
    int*            slot_ord = (int*)alloc(MSLOTS * 4);
    int*            row_src  = (int*)alloc(MSLOTS * 4);
    __hip_bfloat16* Wqbf = (__hip_bfloat16*)alloc((size_t)HDIM * HDIM * 2);    // 2 MB
    __hip_bfloat16* Wkbf = (__hip_bfloat16*)alloc((size_t)HDIM * HDIM * 2);    // 2 MB
    __hip_bfloat16* BbfT = (__hip_bfloat16*)alloc((size_t)HDIM * MSLOTS * 2);  // 16 MB
    // --- Sbf region (64 MB), overlaid with Hbf (8 MB) + Bbf (16 MB), which are
    // CONTIGUOUS (A = [H; B] for the fused projection GEMM) and die before the
    // scores GEMM writes Sbf ---
    size_t s_base = off;
    __hip_bfloat16* Sbf = (__hip_bfloat16*)(ws + s_base);                      // 64 MB
    __hip_bfloat16* Hbf = (__hip_bfloat16*)(ws + s_base);                      //  8 MB
    __hip_bfloat16* Bbf = (__hip_bfloat16*)(ws + s_base + (size_t)BS_CAND * HDIM * 2);
    off = s_base + ((size_t)BS_CAND * MSLOTS * 2 + 255) & ~(size_t)255;
    // --- tail region: qbf+mkbf CONTIGUOUS; PV partials overlay them later ---
    size_t t_base = off;
    __hip_bfloat16* qbf  = (__hip_bfloat16*)alloc((size_t)BS_CAND * HDIM * 2); // 8 MB
    __hip_bfloat16* mkbf = (__hip_bfloat16*)alloc((size_t)MSLOTS * HDIM * 2);  // 16 MB
    __hip_bfloat16* part = (__hip_bfloat16*)(ws + t_base);  // 4 x 8 MB bf16 partials

    // 1) merged prologue: hidden norm+cast | slot keys | Wq/Wk cast
    pre_k<<<BS_CAND + MSLOTS / 256 + 2048, 256, 0, stream>>>(
        hidden, surprise, Hbf, imp, noise, skeys, row_src, Wq, Wqbf, Wk, Wkbf);
    // 2) both rankings in one launch
    ranks_k<<<BS_CAND + MSLOTS, 256, 0, stream>>>(surprise, cand_ord, skeys, slot_ord);
    scatter_k<<<BS_CAND / 256, 256, 0, stream>>>(cand_ord, slot_ord, surprise, row_src);
    // 3) updated memory buffer + its transpose, fused one-pass
    bbt_k<<<dim3(HDIM / 64, MSLOTS / 64), 256, 0, stream>>>(
        membuf, hidden, row_src, Bbf, BbfT);
    // 4) fused projections: [q; mk] = [H; newbuf] @ {Wq,Wk}^T + {bq,bk}
    gemm_bt<1, 0><<<dim3(HDIM / 256, (BS_CAND + MSLOTS) / 256), 512, 131072, stream>>>(
        Hbf, Wqbf, Wkbf, qbf, bq, bk, nullptr, BS_CAND / 256,
        BS_CAND + MSLOTS, HDIM, HDIM, HDIM, 1.f);
    // 5) E = bf16(exp((q @ mk^T)/32)) + per-wave strip sums into ps
    gemm_bt<2, 0><<<dim3(MSLOTS / 256, BS_CAND / 256), 512, 131072, stream>>>(
        qbf, mkbf, nullptr, Sbf, nullptr, nullptr, ps, 1 << 30,
        BS_CAND, MSLOTS, HDIM, HDIM, 0.03125f);
    // 6) split-K PV: bf16 partial[z] = E @ newbuf over K-chunk z
    gemm_bt<4, 1><<<dim3(BS_CAND / 256, HDIM / 256, PV_SPLIT), 512, 131072, stream>>>(
        Sbf, BbfT, nullptr, part, nullptr, nullptr, nullptr, 1 << 30,
        BS_CAND, HDIM, MSLOTS, MSLOTS / PV_SPLIT, 1.f);
    // 7) out = (sum of 4 bf16 partials) / rowsum(ps)   -> fp32 [4096,1024]
    reduce4_k<<<BS_CAND, 256, 0, stream>>>((const ushortx4*)part, ps, (float4*)d_out);
}

// Round 8
// 307.659 us; speedup vs baseline: 2.1116x; 1.0243x over previous
//
#include <hip/hip_runtime.h>
#include <hip/hip_bf16.h>
#include <math.h>
#include <stdint.h>

typedef __attribute__((ext_vector_type(4))) float floatx4;
typedef __attribute__((ext_vector_type(8))) short shortx8;
typedef __attribute__((ext_vector_type(4))) unsigned short ushortx4;

#define BS_CAND 4096   // B*S
#define HDIM    1024
#define MSLOTS  8192
#define THRESH  64.0f
#define PV_SPLIT 4
#define PS_COLS 128    // 32 bn-tiles x 4 n-waves

__device__ __forceinline__ unsigned short f2b_bits(float f) {
    __hip_bfloat16 b = __float2bfloat16(f);
    return *(unsigned short*)&b;
}
__device__ __forceinline__ float b2f_bits(unsigned short u) {
    return __uint_as_float(((unsigned)u) << 16);
}

// ---------------- reduction helper (blockDim == 256) ----------------
__device__ __forceinline__ float blockReduceSum(float x) {
    __shared__ float red[4];
    #pragma unroll
    for (int o = 32; o > 0; o >>= 1) x += __shfl_down(x, o, 64);
    int lane = threadIdx.x & 63, w = threadIdx.x >> 6;
    if (lane == 0) red[w] = x;
    __syncthreads();
    float s = red[0] + red[1] + red[2] + red[3];
    __syncthreads();
    return s;
}

// ------- merged prologue: norm+cast of hidden | slot keys | Wq/Wk cast -------
__global__ __launch_bounds__(256) void pre_k(const float* __restrict__ h,
                                             float* __restrict__ sur,
                                             __hip_bfloat16* __restrict__ Hbf,
                                             const float* __restrict__ imp,
                                             const float* __restrict__ noi,
                                             float* __restrict__ keys,
                                             int* __restrict__ row_src,
                                             const float* __restrict__ Wq,
                                             __hip_bfloat16* __restrict__ Wqbf,
                                             const float* __restrict__ Wk,
                                             __hip_bfloat16* __restrict__ Wkbf) {
    int b = blockIdx.x;
    if (b < BS_CAND) {
        float4 v = ((const float4*)(h + (size_t)b * HDIM))[threadIdx.x];
        ushortx4 o;
        o.x = f2b_bits(v.x); o.y = f2b_bits(v.y);
        o.z = f2b_bits(v.z); o.w = f2b_bits(v.w);
        ((ushortx4*)(Hbf + (size_t)b * HDIM))[threadIdx.x] = o;
        float s = v.x * v.x + v.y * v.y + v.z * v.z + v.w * v.w;
        float tot = blockReduceSum(s);
        if (threadIdx.x == 0) sur[b] = 2.0f * sqrtf(tot);
    } else if (b < BS_CAND + MSLOTS / 256) {
        int i = (b - BS_CAND) * 256 + threadIdx.x;
        keys[i] = imp[i] + noi[i] * 1e-6f;
        row_src[i] = -1;
    } else {
        int w = b - (BS_CAND + MSLOTS / 256);          // 0..2047
        const float* in = (w < 1024) ? Wq : Wk;
        __hip_bfloat16* out = (w < 1024) ? Wqbf : Wkbf;
        int j = (w & 1023) * 256 + threadIdx.x;        // float4 index
        float4 v = ((const float4*)in)[j];
        ushortx4 o;
        o.x = f2b_bits(v.x); o.y = f2b_bits(v.y);
        o.z = f2b_bits(v.z); o.w = f2b_bits(v.w);
        ((ushortx4*)out)[j] = o;
    }
}

// ------------- ranks: 4 elements per BLOCK, register counters -------------
// blocks [0,1024): cand ranks (desc) ; [1024,3072): slot ranks (asc).
// Each thread scans j = tid, tid+256, ... (L1-resident arrays: 16/32 KB),
// updating 4 register counters; 4 block-reductions finish the ranks.
__global__ __launch_bounds__(256) void ranks_k(const float* __restrict__ sur,
                                               int* __restrict__ cand_ord,
                                               const float* __restrict__ keys,
                                               int* __restrict__ slot_ord) {
    const int CB = BS_CAND / 4;                  // 1024 cand blocks
    int b = blockIdx.x;
    bool isSlot = (b >= CB);
    const float* arr = isSlot ? keys : sur;
    int n = isSlot ? MSLOTS : BS_CAND;
    int base = (isSlot ? (b - CB) : b) * 4;
    float k0 = arr[base + 0], k1 = arr[base + 1];
    float k2 = arr[base + 2], k3 = arr[base + 3];
    float c0 = 0.f, c1 = 0.f, c2 = 0.f, c3 = 0.f;
    if (isSlot) {
        for (int j = threadIdx.x; j < n; j += 256) {
            float kj = arr[j];
            c0 += ((kj < k0) || (kj == k0 && j < base + 0)) ? 1.f : 0.f;
            c1 += ((kj < k1) || (kj == k1 && j < base + 1)) ? 1.f : 0.f;
            c2 += ((kj < k2) || (kj == k2 && j < base + 2)) ? 1.f : 0.f;
            c3 += ((kj < k3) || (kj == k3 && j < base + 3)) ? 1.f : 0.f;
        }
    } else {
        for (int j = threadIdx.x; j < n; j += 256) {
            float kj = arr[j];
            c0 += ((kj > k0) || (kj == k0 && j < base + 0)) ? 1.f : 0.f;
            c1 += ((kj > k1) || (kj == k1 && j < base + 1)) ? 1.f : 0.f;
            c2 += ((kj > k2) || (kj == k2 && j < base + 2)) ? 1.f : 0.f;
            c3 += ((kj > k3) || (kj == k3 && j < base + 3)) ? 1.f : 0.f;
        }
    }
    int* ord = isSlot ? slot_ord : cand_ord;
    float r0 = blockReduceSum(c0);
    float r1 = blockReduceSum(c1);
    float r2 = blockReduceSum(c2);
    float r3 = blockReduceSum(c3);
    if (threadIdx.x == 0) {
        ord[(int)r0] = base + 0;
        ord[(int)r1] = base + 1;
        ord[(int)r2] = base + 2;
        ord[(int)r3] = base + 3;
    }
}

// ---------------- scatter: rank-i candidate -> rank-i least-important slot ----
__global__ __launch_bounds__(256) void scatter_k(const int* __restrict__ cand_order,
                                                 const int* __restrict__ slot_order,
                                                 const float* __restrict__ sur,
                                                 int* __restrict__ row_src) {
    int i = blockIdx.x * 256 + threadIdx.x;   // i < BS_CAND
    int c = cand_order[i];
    if (sur[c] > THRESH) row_src[slot_order[i]] = c;
}

// ------ merged build+transpose: Bbf row-major AND BbfT, one pass ------
__global__ __launch_bounds__(256) void bbt_k(const float* __restrict__ mem,
                                             const float* __restrict__ hid,
                                             const int* __restrict__ src,
                                             __hip_bfloat16* __restrict__ B,
                                             __hip_bfloat16* __restrict__ BT) {
    __shared__ unsigned short t[64][72];
    int cb = blockIdx.x * 64, rb = blockIdx.y * 64;
    int tx = threadIdx.x & 63, ty = threadIdx.x >> 6;
    #pragma unroll
    for (int k = 0; k < 16; k++) {
        int r = ty * 16 + k;
        int s = src[rb + r];
        const float* row = (s < 0) ? (mem + (size_t)(rb + r) * HDIM)
                                   : (hid + (size_t)s * HDIM);
        unsigned short b = f2b_bits(row[cb + tx]);
        t[r][tx] = b;
        ((unsigned short*)B)[(size_t)(rb + r) * HDIM + cb + tx] = b;
    }
    __syncthreads();
    #pragma unroll
    for (int k = 0; k < 16; k++) {
        int c = ty * 16 + k;
        ((unsigned short*)BT)[(size_t)(cb + c) * MSLOTS + rb + tx] = t[tx][c];
    }
}

// ---------------- async global->LDS helper ----------------
__device__ __forceinline__ void load_lds16(const __hip_bfloat16* g, __hip_bfloat16* l) {
    __builtin_amdgcn_global_load_lds(
        (const __attribute__((address_space(1))) void*)g,
        (__attribute__((address_space(3))) void*)l, 16, 0, 0);
}

// =====================================================================
// 256x256 8-phase BT-GEMM (T2+T3+T4+T5): R4-verified structure (312 us):
// 512 thr = 8 waves (2Mx4N), BK=64, 2 K-tiles/iter, 128 KiB LDS double
// buffer, XOR-swizzle on pre-swizzled GLOBAL source + same XOR on ds_read
// (conflicts measured 0), counted vmcnt(6) at ph4/ph8 only, B-halves held
// in regs (no ph4/ph8 re-read), setprio around MFMA.
// R7: XCD-aware block swizzle for SWAP==0 (T1): linear wgid -> each XCD
// gets a contiguous chunk of (bm,bn) tiles (bn-fastest) so the qbf/Hbf
// A-panels pin in that XCD's L2. Requires nwg%8==0 (scores 512, proj 192
// both OK). SWAP==1 (PV) keeps the natural mapping (bm%8 already
// clusters the A-sharing blocks per XCD).
// EPI 1: out = bf16(acc + biasSel[col]); Bt/bias switch at bm==rows0b
// EPI 2: out = bf16(exp(acc*scale)); per-wave 64-col strip sums -> ps
// EPI 4: out[z*M*N + idx] = bf16(acc*scale)  (bf16 split-K partial)
// =====================================================================
template <int EPI, int SWAP>
__global__ __launch_bounds__(512, 2) void gemm_bt(const __hip_bfloat16* __restrict__ A,
                                                  const __hip_bfloat16* __restrict__ Bt,
                                                  const __hip_bfloat16* __restrict__ Bt2,
                                                  __hip_bfloat16* __restrict__ outH,
                                                  const float* __restrict__ bias,
                                                  const float* __restrict__ bias2,
                                                  float* __restrict__ ps,
                                                  int rows0b, int bnshift,
                                                  int M, int N, int K, int ksplit,
                                                  float scale) {
    extern __shared__ char lds[];
    const int tid = threadIdx.x;
    const int wave = tid >> 6, lane = tid & 63;
    const int lm = lane & 15, lq = lane >> 4;
    const int wm = wave >> 2, wn = wave & 3;
    int bm, bn;
    if (SWAP) {                       // PV: natural mapping already XCD-groups A
        bm = blockIdx.x; bn = blockIdx.y;
    } else {                          // T1 bijective XCD swizzle (nwg%8==0)
        const int lin = blockIdx.x + (blockIdx.y << bnshift);
        const int nwg8 = (gridDim.x * gridDim.y) >> 3;
        const int swz = (lin & 7) * nwg8 + (lin >> 3);
        bn = swz & (gridDim.x - 1);
        bm = swz >> bnshift;
    }
    const int kb = blockIdx.z * ksplit;
    const int niters = ksplit >> 7;            // 128 of K per iteration

    const __hip_bfloat16* BtSel = (EPI == 1 && bm >= rows0b) ? Bt2 : Bt;
    const float* biasSel = (EPI == 1 && bm >= rows0b) ? bias2 : bias;

    // ---- per-thread staging source pointers (pre-swizzled global src) ----
    const int l8 = lane >> 3;
    const int colsrc = ((((lane & 7) << 4) ^ (l8 << 4)) >> 1);
    const __hip_bfloat16* Abase = A + (size_t)bm * 256 * K;
    const __hip_bfloat16* Bbase = BtSel + (size_t)bn * 256 * K;
    const __hip_bfloat16* srcA[2][2];
    const __hip_bfloat16* srcB[2][2];
    #pragma unroll
    for (int h = 0; h < 2; h++)
        #pragma unroll
        for (int t = 0; t < 2; t++) {
            int row = t * 128 + h * 64 + wave * 8 + l8;
            srcA[h][t] = Abase + (size_t)row * K + colsrc;
            srcB[h][t] = Bbase + (size_t)row * K + colsrc;
        }

    // ---- ds_read fragment byte offsets (swizzled) ----
    const int cxor = (lq << 4) ^ ((lm & 7) << 4);
    const int a_b0 = (wm * 64 + lm) * 128 + cxor;
    const int a_b1 = a_b0 ^ 64;
    const int b_b0 = (wn * 32 + lm) * 128 + cxor;
    const int b_b1 = b_b0 ^ 64;

    floatx4 acc[8][4];
    #pragma unroll
    for (int i = 0; i < 8; i++)
        #pragma unroll
        for (int j = 0; j < 4; j++) acc[i][j] = {0.f, 0.f, 0.f, 0.f};

    shortx8 af[4][2], bf0h[2][2], bf1h[2][2];

#define LDSV(off) (*(const shortx8*)(lds + (off)))
#define READ_A(g, bo) do {                                                  \
    const int ab_ = (bo) + (g) * 16384;                                     \
    af[0][0] = LDSV(ab_ + a_b0);        af[0][1] = LDSV(ab_ + a_b1);        \
    af[1][0] = LDSV(ab_ + a_b0 + 2048); af[1][1] = LDSV(ab_ + a_b1 + 2048); \
    af[2][0] = LDSV(ab_ + a_b0 + 4096); af[2][1] = LDSV(ab_ + a_b1 + 4096); \
    af[3][0] = LDSV(ab_ + a_b0 + 6144); af[3][1] = LDSV(ab_ + a_b1 + 6144); \
} while (0)
#define READ_B(dst, g, bo) do {                                             \
    const int bb_ = (bo) + 32768 + (g) * 16384;                             \
    dst[0][0] = LDSV(bb_ + b_b0);        dst[0][1] = LDSV(bb_ + b_b1);      \
    dst[1][0] = LDSV(bb_ + b_b0 + 2048); dst[1][1] = LDSV(bb_ + b_b1 + 2048);\
} while (0)
#define STAGE(xs, h, buf, kofs) do {                                        \
    char* d_ = lds + (buf) * 65536 + (xs) * 32768 + (h) * 16384 + wave * 1024; \
    load_lds16(((xs) ? srcB : srcA)[h][0] + (kofs), (__hip_bfloat16*)d_);   \
    load_lds16(((xs) ? srcB : srcA)[h][1] + (kofs), (__hip_bfloat16*)(d_ + 8192)); \
} while (0)
#define MFQ(mh, nh, BF) do {                                                \
    __builtin_amdgcn_s_setprio(1);                                          \
    _Pragma("unroll")                                                       \
    for (int ii_ = 0; ii_ < 4; ii_++)                                       \
        _Pragma("unroll")                                                   \
        for (int jj_ = 0; jj_ < 2; jj_++) {                                 \
            acc[(mh)*4+ii_][(nh)*2+jj_] = __builtin_amdgcn_mfma_f32_16x16x32_bf16( \
                af[ii_][0], BF[jj_][0], acc[(mh)*4+ii_][(nh)*2+jj_], 0, 0, 0); \
            acc[(mh)*4+ii_][(nh)*2+jj_] = __builtin_amdgcn_mfma_f32_16x16x32_bf16( \
                af[ii_][1], BF[jj_][1], acc[(mh)*4+ii_][(nh)*2+jj_], 0, 0, 0); \
        }                                                                   \
    __builtin_amdgcn_s_setprio(0);                                          \
} while (0)
#define BAR() __builtin_amdgcn_s_barrier()
#define LGKM0() asm volatile("s_waitcnt lgkmcnt(0)" ::: "memory")
#define VMC6() asm volatile("s_waitcnt vmcnt(6)" ::: "memory")
#define VMC0() asm volatile("s_waitcnt vmcnt(0)" ::: "memory")

    // ---- prologue: stage buf0 fully + buf1.{A0,B1,A1}; order matches
    // steady-state issue order so vmcnt counting lines up ----
    STAGE(0, 0, 0, kb);        // buf0.A0
    STAGE(1, 1, 0, kb);        // buf0.B1
    STAGE(0, 1, 0, kb);        // buf0.A1
    STAGE(1, 0, 0, kb);        // buf0.B0
    STAGE(0, 0, 1, kb + 64);   // buf1.A0
    STAGE(1, 1, 1, kb + 64);   // buf1.B1
    STAGE(0, 1, 1, kb + 64);   // buf1.A1
    VMC6();                    // buf0 landed, 3 halves in flight
    BAR();

#define ITER(E, kcur, knext) do {                                           \
    /* ph1 */                                                               \
    READ_A(0, 0); READ_B(bf0h, 0, 0); STAGE(1, 0, 1, (kcur) + 64);          \
    BAR(); LGKM0(); MFQ(0, 0, bf0h); BAR();                                 \
    /* ph2 */                                                               \
    READ_B(bf1h, 1, 0); if (E) STAGE(0, 0, 0, (knext));                     \
    BAR(); LGKM0(); MFQ(0, 1, bf1h); BAR();                                 \
    /* ph3 */                                                               \
    READ_A(1, 0); if (E) STAGE(1, 1, 0, (knext));                           \
    BAR(); LGKM0(); MFQ(1, 1, bf1h); BAR();                                 \
    /* ph4 (B0 held in bf0h: no re-read) */                                 \
    if (E) { STAGE(0, 1, 0, (knext)); VMC6(); } else { VMC0(); }            \
    BAR(); LGKM0(); MFQ(1, 0, bf0h); BAR();                                 \
    /* ph5 */                                                               \
    READ_A(0, 65536); READ_B(bf0h, 0, 65536); if (E) STAGE(1, 0, 0, (knext)); \
    BAR(); LGKM0(); MFQ(0, 0, bf0h); BAR();                                 \
    /* ph6 */                                                               \
    READ_B(bf1h, 1, 65536); if (E) STAGE(0, 0, 1, (knext) + 64);            \
    BAR(); LGKM0(); MFQ(0, 1, bf1h); BAR();                                 \
    /* ph7 */                                                               \
    READ_A(1, 65536); if (E) STAGE(1, 1, 1, (knext) + 64);                  \
    BAR(); LGKM0(); MFQ(1, 1, bf1h); BAR();                                 \
    /* ph8 (B0 held) */                                                     \
    if (E) { STAGE(0, 1, 1, (knext) + 64); VMC6(); }                        \
    BAR(); LGKM0(); MFQ(1, 0, bf0h); BAR();                                 \
} while (0)

    int it = 0;
    #pragma unroll 1
    for (; it < niters - 1; ++it) {
        const int kc = kb + it * 128;
        ITER(1, kc, kc + 128);
    }
    {   // last iteration: no next-tile staging, full drain at ph4
        const int kc = kb + it * 128;
        ITER(0, kc, 0);
    }

#undef ITER
#undef LDSV
#undef READ_A
#undef READ_B
#undef STAGE
#undef MFQ
#undef BAR
#undef LGKM0
#undef VMC6
#undef VMC0

    // ---- epilogue (round-1 verified direct stores) ----
    // row = bm*256 + wm*128 + (i>>2)*64 + (i&3)*16 + lq*4 + r
    // col = bn*256 + (wn>>1)*128 + (j>>1)*64 + (wn&1)*32 + (j&1)*16 + lm
    if (EPI == 2) {
        #pragma unroll
        for (int i = 0; i < 8; i++) {
            const int grow0 = bm * 256 + wm * 128 + (i >> 2) * 64 + (i & 3) * 16 + lq * 4;
            #pragma unroll
            for (int r = 0; r < 4; r++) {
                float rs = 0.f;
                #pragma unroll
                for (int j = 0; j < 4; j++) {
                    const int gcol = bn * 256 + (wn >> 1) * 128 + (j >> 1) * 64 +
                                     (wn & 1) * 32 + (j & 1) * 16 + lm;
                    float e = __expf(acc[i][j][r] * scale);
                    unsigned short eb = f2b_bits(e);
                    ((unsigned short*)outH)[(size_t)(grow0 + r) * N + gcol] = eb;
                    rs += b2f_bits(eb);
                }
                rs += __shfl_xor(rs, 1, 64);
                rs += __shfl_xor(rs, 2, 64);
                rs += __shfl_xor(rs, 4, 64);
                rs += __shfl_xor(rs, 8, 64);
                if (lm == 0)
                    ps[(size_t)(grow0 + r) * PS_COLS + bn * 4 + wn] = rs;
            }
        }
    } else {
        __hip_bfloat16* outHz = outH + ((EPI == 4) ? (size_t)blockIdx.z * M * N : 0);
        #pragma unroll
        for (int i = 0; i < 8; i++) {
            const int grow0 = bm * 256 + wm * 128 + (i >> 2) * 64 + (i & 3) * 16 + lq * 4;
            #pragma unroll
            for (int j = 0; j < 4; j++) {
                const int gcol = bn * 256 + (wn >> 1) * 128 + (j >> 1) * 64 +
                                 (wn & 1) * 32 + (j & 1) * 16 + lm;
                #pragma unroll
                for (int r = 0; r < 4; r++) {
                    float v = acc[i][j][r];
                    size_t idx = (size_t)(grow0 + r) * N + gcol;
                    if (EPI == 1) outHz[idx] = __float2bfloat16(v + biasSel[gcol]);
                    else          outHz[idx] = __float2bfloat16(v * scale);
                }
            }
        }
    }
}

// ------- final: out[row] = (sum of bf16 partials) / (sum of ps[row][*]) -------
__global__ __launch_bounds__(256) void reduce4_k(const ushortx4* __restrict__ part,
                                                 const float* __restrict__ ps,
                                                 float4* __restrict__ out) {
    int row = blockIdx.x;
    float s = 0.f;
    if (threadIdx.x < PS_COLS) s = ps[(size_t)row * PS_COLS + threadIdx.x];
    float tot = blockReduceSum(s);
    float inv = 1.f / tot;
    size_t base = (size_t)row * (HDIM / 4) + threadIdx.x;
    const size_t stride = (size_t)BS_CAND * (HDIM / 4);
    float4 o = {0.f, 0.f, 0.f, 0.f};
    #pragma unroll
    for (int z = 0; z < PV_SPLIT; z++) {
        ushortx4 p = part[base + (size_t)z * stride];
        o.x += b2f_bits(p.x); o.y += b2f_bits(p.y);
        o.z += b2f_bits(p.z); o.w += b2f_bits(p.w);
    }
    o.x *= inv; o.y *= inv; o.z *= inv; o.w *= inv;
    out[(size_t)row * (HDIM / 4) + threadIdx.x] = o;
}

// ---------------- launch ----------------
extern "C" void kernel_launch(void* const* d_in, const int* in_sizes, int n_in,
                              void* d_out, int out_size, void* d_ws, size_t ws_size,
                              hipStream_t stream) {
    const float* hidden = (const float*)d_in[0];   // [2,2048,1024]
    const float* membuf = (const float*)d_in[1];   // [8192,1024]
    const float* imp    = (const float*)d_in[2];   // [8192]
    const float* Wq     = (const float*)d_in[3];   // [1024,1024]
    const float* bq     = (const float*)d_in[4];   // [1024]
    const float* Wk     = (const float*)d_in[5];   // [1024,1024]
    const float* bk     = (const float*)d_in[6];   // [1024]
    const float* noise  = (const float*)d_in[7];   // [8192]

    // 128 KiB dynamic LDS needs the opt-in attribute (once per process)
    static bool s_attr = false;
    if (!s_attr) {
        (void)hipFuncSetAttribute((const void*)gemm_bt<1, 0>,
                                  hipFuncAttributeMaxDynamicSharedMemorySize, 131072);
        (void)hipFuncSetAttribute((const void*)gemm_bt<2, 0>,
                                  hipFuncAttributeMaxDynamicSharedMemorySize, 131072);
        (void)hipFuncSetAttribute((const void*)gemm_bt<4, 1>,
                                  hipFuncAttributeMaxDynamicSharedMemorySize, 131072);
        s_attr = true;
    }

    char* ws = (char*)d_ws;
    size_t off = 0;
    auto alloc = [&](size_t bytes) -> void* {
        void* p = ws + off;
        off += (bytes + 255) & ~(size_t)255;
        return p;
    };
    // --- persistent region (front) ---
    float*          surprise = (float*)alloc(BS_CAND * 4);
    float*          skeys    = (float*)alloc(MSLOTS * 4);
    float*          ps       = (float*)alloc((size_t)BS_CAND * PS_COLS * 4);   // 2 MB
    int*            cand_ord = (int*)alloc(BS_CAND * 4);
    int*            slot_ord = (int*)alloc(MSLOTS * 4);
    int*            row_src  = (int*)alloc(MSLOTS * 4);
    __hip_bfloat16* Wqbf = (__hip_bfloat16*)alloc((size_t)HDIM * HDIM * 2);    // 2 MB
    __hip_bfloat16* Wkbf = (__hip_bfloat16*)alloc((size_t)HDIM * HDIM * 2);    // 2 MB
    __hip_bfloat16* BbfT = (__hip_bfloat16*)alloc((size_t)HDIM * MSLOTS * 2);  // 16 MB
    // --- Sbf region (64 MB), overlaid with Hbf (8 MB) + Bbf (16 MB), which are
    // CONTIGUOUS (A = [H; B] for the fused projection GEMM) and die before the
    // scores GEMM writes Sbf ---
    size_t s_base = off;
    __hip_bfloat16* Sbf = (__hip_bfloat16*)(ws + s_base);                      // 64 MB
    __hip_bfloat16* Hbf = (__hip_bfloat16*)(ws + s_base);                      //  8 MB
    __hip_bfloat16* Bbf = (__hip_bfloat16*)(ws + s_base + (size_t)BS_CAND * HDIM * 2);
    off = s_base + ((size_t)BS_CAND * MSLOTS * 2 + 255) & ~(size_t)255;
    // --- tail region: qbf+mkbf CONTIGUOUS; PV partials overlay them later ---
    size_t t_base = off;
    __hip_bfloat16* qbf  = (__hip_bfloat16*)alloc((size_t)BS_CAND * HDIM * 2); // 8 MB
    __hip_bfloat16* mkbf = (__hip_bfloat16*)alloc((size_t)MSLOTS * HDIM * 2);  // 16 MB
    __hip_bfloat16* part = (__hip_bfloat16*)(ws + t_base);  // 4 x 8 MB bf16 partials

    // 1) merged prologue: hidden norm+cast | slot keys | Wq/Wk cast
    pre_k<<<BS_CAND + MSLOTS / 256 + 2048, 256, 0, stream>>>(
        hidden, surprise, Hbf, imp, noise, skeys, row_src, Wq, Wqbf, Wk, Wkbf);
    // 2) both rankings: 4 elems/block, register counters
    ranks_k<<<(BS_CAND + MSLOTS) / 4, 256, 0, stream>>>(
        surprise, cand_ord, skeys, slot_ord);
    scatter_k<<<BS_CAND / 256, 256, 0, stream>>>(cand_ord, slot_ord, surprise, row_src);
    // 3) updated memory buffer + its transpose, fused one-pass
    bbt_k<<<dim3(HDIM / 64, MSLOTS / 64), 256, 0, stream>>>(
        membuf, hidden, row_src, Bbf, BbfT);
    // 4) fused projections: [q; mk] = [H; newbuf] @ {Wq,Wk}^T + {bq,bk}
    //    grid 4x48=192 blocks (nwg%8==0), bnshift=log2(4)=2
    gemm_bt<1, 0><<<dim3(HDIM / 256, (BS_CAND + MSLOTS) / 256), 512, 131072, stream>>>(
        Hbf, Wqbf, Wkbf, qbf, bq, bk, nullptr, BS_CAND / 256, 2,
        BS_CAND + MSLOTS, HDIM, HDIM, HDIM, 1.f);
    // 5) E = bf16(exp((q @ mk^T)/32)) + per-wave strip sums into ps
    //    grid 32x16=512 blocks (nwg%8==0), bnshift=log2(32)=5
    gemm_bt<2, 0><<<dim3(MSLOTS / 256, BS_CAND / 256), 512, 131072, stream>>>(
        qbf, mkbf, nullptr, Sbf, nullptr, nullptr, ps, 1 << 30, 5,
        BS_CAND, MSLOTS, HDIM, HDIM, 0.03125f);
    // 6) split-K PV: bf16 partial[z] = E @ newbuf over K-chunk z
    gemm_bt<4, 1><<<dim3(BS_CAND / 256, HDIM / 256, PV_SPLIT), 512, 131072, stream>>>(
        Sbf, BbfT, nullptr, part, nullptr, nullptr, nullptr, 1 << 30, 0,
        BS_CAND, HDIM, MSLOTS, MSLOTS / PV_SPLIT, 1.f);
    // 7) out = (sum of 4 bf16 partials) / rowsum(ps)   -> fp32 [4096,1024]
    reduce4_k<<<BS_CAND, 256, 0, stream>>>((const ushortx4*)part, ps, (float4*)d_out);
}

// Round 9
// 303.661 us; speedup vs baseline: 2.1394x; 1.0132x over previous
//
#include <hip/hip_runtime.h>
#include <hip/hip_bf16.h>
#include <math.h>
#include <stdint.h>

typedef __attribute__((ext_vector_type(4))) float floatx4;
typedef __attribute__((ext_vector_type(8))) short shortx8;
typedef __attribute__((ext_vector_type(4))) unsigned short ushortx4;

#define BS_CAND 4096   // B*S
#define HDIM    1024
#define MSLOTS  8192
#define THRESH  64.0f
#define PV_SPLIT 4
#define PS_COLS 128    // 32 bn-tiles x 4 n-waves

__device__ __forceinline__ unsigned short f2b_bits(float f) {
    __hip_bfloat16 b = __float2bfloat16(f);
    return *(unsigned short*)&b;
}
__device__ __forceinline__ float b2f_bits(unsigned short u) {
    return __uint_as_float(((unsigned)u) << 16);
}

// ---------------- reduction helper (blockDim == 256) ----------------
__device__ __forceinline__ float blockReduceSum(float x) {
    __shared__ float red[4];
    #pragma unroll
    for (int o = 32; o > 0; o >>= 1) x += __shfl_down(x, o, 64);
    int lane = threadIdx.x & 63, w = threadIdx.x >> 6;
    if (lane == 0) red[w] = x;
    __syncthreads();
    float s = red[0] + red[1] + red[2] + red[3];
    __syncthreads();
    return s;
}

// ------- merged prologue: norm+cast of hidden | slot keys | Wq/Wk cast -------
__global__ __launch_bounds__(256) void pre_k(const float* __restrict__ h,
                                             float* __restrict__ sur,
                                             __hip_bfloat16* __restrict__ Hbf,
                                             const float* __restrict__ imp,
                                             const float* __restrict__ noi,
                                             float* __restrict__ keys,
                                             int* __restrict__ row_src,
                                             const float* __restrict__ Wq,
                                             __hip_bfloat16* __restrict__ Wqbf,
                                             const float* __restrict__ Wk,
                                             __hip_bfloat16* __restrict__ Wkbf) {
    int b = blockIdx.x;
    if (b < BS_CAND) {
        float4 v = ((const float4*)(h + (size_t)b * HDIM))[threadIdx.x];
        ushortx4 o;
        o.x = f2b_bits(v.x); o.y = f2b_bits(v.y);
        o.z = f2b_bits(v.z); o.w = f2b_bits(v.w);
        ((ushortx4*)(Hbf + (size_t)b * HDIM))[threadIdx.x] = o;
        float s = v.x * v.x + v.y * v.y + v.z * v.z + v.w * v.w;
        float tot = blockReduceSum(s);
        if (threadIdx.x == 0) sur[b] = 2.0f * sqrtf(tot);
    } else if (b < BS_CAND + MSLOTS / 256) {
        int i = (b - BS_CAND) * 256 + threadIdx.x;
        keys[i] = imp[i] + noi[i] * 1e-6f;
        row_src[i] = -1;
    } else {
        int w = b - (BS_CAND + MSLOTS / 256);          // 0..2047
        const float* in = (w < 1024) ? Wq : Wk;
        __hip_bfloat16* out = (w < 1024) ? Wqbf : Wkbf;
        int j = (w & 1023) * 256 + threadIdx.x;        // float4 index
        float4 v = ((const float4*)in)[j];
        ushortx4 o;
        o.x = f2b_bits(v.x); o.y = f2b_bits(v.y);
        o.z = f2b_bits(v.z); o.w = f2b_bits(v.w);
        ((ushortx4*)out)[j] = o;
    }
}

// ------------- ranks: 4 elements per BLOCK, register counters -------------
// blocks [0,1024): cand ranks (desc) ; [1024,3072): slot ranks (asc).
__global__ __launch_bounds__(256) void ranks_k(const float* __restrict__ sur,
                                               int* __restrict__ cand_ord,
                                               const float* __restrict__ keys,
                                               int* __restrict__ slot_ord) {
    const int CB = BS_CAND / 4;                  // 1024 cand blocks
    int b = blockIdx.x;
    bool isSlot = (b >= CB);
    const float* arr = isSlot ? keys : sur;
    int n = isSlot ? MSLOTS : BS_CAND;
    int base = (isSlot ? (b - CB) : b) * 4;
    float k0 = arr[base + 0], k1 = arr[base + 1];
    float k2 = arr[base + 2], k3 = arr[base + 3];
    float c0 = 0.f, c1 = 0.f, c2 = 0.f, c3 = 0.f;
    if (isSlot) {
        for (int j = threadIdx.x; j < n; j += 256) {
            float kj = arr[j];
            c0 += ((kj < k0) || (kj == k0 && j < base + 0)) ? 1.f : 0.f;
            c1 += ((kj < k1) || (kj == k1 && j < base + 1)) ? 1.f : 0.f;
            c2 += ((kj < k2) || (kj == k2 && j < base + 2)) ? 1.f : 0.f;
            c3 += ((kj < k3) || (kj == k3 && j < base + 3)) ? 1.f : 0.f;
        }
    } else {
        for (int j = threadIdx.x; j < n; j += 256) {
            float kj = arr[j];
            c0 += ((kj > k0) || (kj == k0 && j < base + 0)) ? 1.f : 0.f;
            c1 += ((kj > k1) || (kj == k1 && j < base + 1)) ? 1.f : 0.f;
            c2 += ((kj > k2) || (kj == k2 && j < base + 2)) ? 1.f : 0.f;
            c3 += ((kj > k3) || (kj == k3 && j < base + 3)) ? 1.f : 0.f;
        }
    }
    int* ord = isSlot ? slot_ord : cand_ord;
    float r0 = blockReduceSum(c0);
    float r1 = blockReduceSum(c1);
    float r2 = blockReduceSum(c2);
    float r3 = blockReduceSum(c3);
    if (threadIdx.x == 0) {
        ord[(int)r0] = base + 0;
        ord[(int)r1] = base + 1;
        ord[(int)r2] = base + 2;
        ord[(int)r3] = base + 3;
    }
}

// ---------------- scatter: rank-i candidate -> rank-i least-important slot ----
__global__ __launch_bounds__(256) void scatter_k(const int* __restrict__ cand_order,
                                                 const int* __restrict__ slot_order,
                                                 const float* __restrict__ sur,
                                                 int* __restrict__ row_src) {
    int i = blockIdx.x * 256 + threadIdx.x;   // i < BS_CAND
    int c = cand_order[i];
    if (sur[c] > THRESH) row_src[slot_order[i]] = c;
}

// ------ merged build+transpose: Bbf row-major AND BbfT, one pass ------
__global__ __launch_bounds__(256) void bbt_k(const float* __restrict__ mem,
                                             const float* __restrict__ hid,
                                             const int* __restrict__ src,
                                             __hip_bfloat16* __restrict__ B,
                                             __hip_bfloat16* __restrict__ BT) {
    __shared__ unsigned short t[64][72];
    int cb = blockIdx.x * 64, rb = blockIdx.y * 64;
    int tx = threadIdx.x & 63, ty = threadIdx.x >> 6;
    #pragma unroll
    for (int k = 0; k < 16; k++) {
        int r = ty * 16 + k;
        int s = src[rb + r];
        const float* row = (s < 0) ? (mem + (size_t)(rb + r) * HDIM)
                                   : (hid + (size_t)s * HDIM);
        unsigned short b = f2b_bits(row[cb + tx]);
        t[r][tx] = b;
        ((unsigned short*)B)[(size_t)(rb + r) * HDIM + cb + tx] = b;
    }
    __syncthreads();
    #pragma unroll
    for (int k = 0; k < 16; k++) {
        int c = ty * 16 + k;
        ((unsigned short*)BT)[(size_t)(cb + c) * MSLOTS + rb + tx] = t[tx][c];
    }
}

// ---------------- async global->LDS helper ----------------
__device__ __forceinline__ void load_lds16(const __hip_bfloat16* g, __hip_bfloat16* l) {
    __builtin_amdgcn_global_load_lds(
        (const __attribute__((address_space(1))) void*)g,
        (__attribute__((address_space(3))) void*)l, 16, 0, 0);
}

// =====================================================================
// 256x256 8-phase BT-GEMM (T2+T3+T4+T5): R4-verified structure (312 us):
// 512 thr = 8 waves (2Mx4N), BK=64, 2 K-tiles/iter, 128 KiB LDS double
// buffer, XOR-swizzle on pre-swizzled GLOBAL source + same XOR on ds_read
// (conflicts measured 0), counted vmcnt(6) at ph4/ph8 only, B-halves held
// in regs (no ph4/ph8 re-read), setprio around MFMA.
// R9: XCD swizzle REVERTED (R8 measured FETCH 49->135 MB, dur +2us: the
// natural round-robin mapping already pins the 4-per-XCD B-panels in L2;
// chunked swizzle destroyed B-reuse). Natural blockIdx mapping everywhere.
// EPI 1: out = bf16(acc + biasSel[col]); Bt/bias switch at bm==rows0b
// EPI 2: out = bf16(exp(acc*scale)); per-wave 64-col strip sums -> ps
// EPI 4: out[z*M*N + idx] = bf16(acc*scale)  (bf16 split-K partial)
// =====================================================================
template <int EPI, int SWAP>
__global__ __launch_bounds__(512, 2) void gemm_bt(const __hip_bfloat16* __restrict__ A,
                                                  const __hip_bfloat16* __restrict__ Bt,
                                                  const __hip_bfloat16* __restrict__ Bt2,
                                                  __hip_bfloat16* __restrict__ outH,
                                                  const float* __restrict__ bias,
                                                  const float* __restrict__ bias2,
                                                  float* __restrict__ ps,
                                                  int rows0b,
                                                  int M, int N, int K, int ksplit,
                                                  float scale) {
    extern __shared__ char lds[];
    const int tid = threadIdx.x;
    const int wave = tid >> 6, lane = tid & 63;
    const int lm = lane & 15, lq = lane >> 4;
    const int wm = wave >> 2, wn = wave & 3;
    const int bm = SWAP ? blockIdx.x : blockIdx.y;
    const int bn = SWAP ? blockIdx.y : blockIdx.x;
    const int kb = blockIdx.z * ksplit;
    const int niters = ksplit >> 7;            // 128 of K per iteration

    const __hip_bfloat16* BtSel = (EPI == 1 && bm >= rows0b) ? Bt2 : Bt;
    const float* biasSel = (EPI == 1 && bm >= rows0b) ? bias2 : bias;

    // ---- per-thread staging source pointers (pre-swizzled global src) ----
    const int l8 = lane >> 3;
    const int colsrc = ((((lane & 7) << 4) ^ (l8 << 4)) >> 1);
    const __hip_bfloat16* Abase = A + (size_t)bm * 256 * K;
    const __hip_bfloat16* Bbase = BtSel + (size_t)bn * 256 * K;
    const __hip_bfloat16* srcA[2][2];
    const __hip_bfloat16* srcB[2][2];
    #pragma unroll
    for (int h = 0; h < 2; h++)
        #pragma unroll
        for (int t = 0; t < 2; t++) {
            int row = t * 128 + h * 64 + wave * 8 + l8;
            srcA[h][t] = Abase + (size_t)row * K + colsrc;
            srcB[h][t] = Bbase + (size_t)row * K + colsrc;
        }

    // ---- ds_read fragment byte offsets (swizzled) ----
    const int cxor = (lq << 4) ^ ((lm & 7) << 4);
    const int a_b0 = (wm * 64 + lm) * 128 + cxor;
    const int a_b1 = a_b0 ^ 64;
    const int b_b0 = (wn * 32 + lm) * 128 + cxor;
    const int b_b1 = b_b0 ^ 64;

    floatx4 acc[8][4];
    #pragma unroll
    for (int i = 0; i < 8; i++)
        #pragma unroll
        for (int j = 0; j < 4; j++) acc[i][j] = {0.f, 0.f, 0.f, 0.f};

    shortx8 af[4][2], bf0h[2][2], bf1h[2][2];

#define LDSV(off) (*(const shortx8*)(lds + (off)))
#define READ_A(g, bo) do {                                                  \
    const int ab_ = (bo) + (g) * 16384;                                     \
    af[0][0] = LDSV(ab_ + a_b0);        af[0][1] = LDSV(ab_ + a_b1);        \
    af[1][0] = LDSV(ab_ + a_b0 + 2048); af[1][1] = LDSV(ab_ + a_b1 + 2048); \
    af[2][0] = LDSV(ab_ + a_b0 + 4096); af[2][1] = LDSV(ab_ + a_b1 + 4096); \
    af[3][0] = LDSV(ab_ + a_b0 + 6144); af[3][1] = LDSV(ab_ + a_b1 + 6144); \
} while (0)
#define READ_B(dst, g, bo) do {                                             \
    const int bb_ = (bo) + 32768 + (g) * 16384;                             \
    dst[0][0] = LDSV(bb_ + b_b0);        dst[0][1] = LDSV(bb_ + b_b1);      \
    dst[1][0] = LDSV(bb_ + b_b0 + 2048); dst[1][1] = LDSV(bb_ + b_b1 + 2048);\
} while (0)
#define STAGE(xs, h, buf, kofs) do {                                        \
    char* d_ = lds + (buf) * 65536 + (xs) * 32768 + (h) * 16384 + wave * 1024; \
    load_lds16(((xs) ? srcB : srcA)[h][0] + (kofs), (__hip_bfloat16*)d_);   \
    load_lds16(((xs) ? srcB : srcA)[h][1] + (kofs), (__hip_bfloat16*)(d_ + 8192)); \
} while (0)
#define MFQ(mh, nh, BF) do {                                                \
    __builtin_amdgcn_s_setprio(1);                                          \
    _Pragma("unroll")                                                       \
    for (int ii_ = 0; ii_ < 4; ii_++)                                       \
        _Pragma("unroll")                                                   \
        for (int jj_ = 0; jj_ < 2; jj_++) {                                 \
            acc[(mh)*4+ii_][(nh)*2+jj_] = __builtin_amdgcn_mfma_f32_16x16x32_bf16( \
                af[ii_][0], BF[jj_][0], acc[(mh)*4+ii_][(nh)*2+jj_], 0, 0, 0); \
            acc[(mh)*4+ii_][(nh)*2+jj_] = __builtin_amdgcn_mfma_f32_16x16x32_bf16( \
                af[ii_][1], BF[jj_][1], acc[(mh)*4+ii_][(nh)*2+jj_], 0, 0, 0); \
        }                                                                   \
    __builtin_amdgcn_s_setprio(0);                                          \
} while (0)
#define BAR() __builtin_amdgcn_s_barrier()
#define LGKM0() asm volatile("s_waitcnt lgkmcnt(0)" ::: "memory")
#define VMC6() asm volatile("s_waitcnt vmcnt(6)" ::: "memory")
#define VMC0() asm volatile("s_waitcnt vmcnt(0)" ::: "memory")

    // ---- prologue: stage buf0 fully + buf1.{A0,B1,A1}; order matches
    // steady-state issue order so vmcnt counting lines up ----
    STAGE(0, 0, 0, kb);        // buf0.A0
    STAGE(1, 1, 0, kb);        // buf0.B1
    STAGE(0, 1, 0, kb);        // buf0.A1
    STAGE(1, 0, 0, kb);        // buf0.B0
    STAGE(0, 0, 1, kb + 64);   // buf1.A0
    STAGE(1, 1, 1, kb + 64);   // buf1.B1
    STAGE(0, 1, 1, kb + 64);   // buf1.A1
    VMC6();                    // buf0 landed, 3 halves in flight
    BAR();

#define ITER(E, kcur, knext) do {                                           \
    /* ph1 */                                                               \
    READ_A(0, 0); READ_B(bf0h, 0, 0); STAGE(1, 0, 1, (kcur) + 64);          \
    BAR(); LGKM0(); MFQ(0, 0, bf0h); BAR();                                 \
    /* ph2 */                                                               \
    READ_B(bf1h, 1, 0); if (E) STAGE(0, 0, 0, (knext));                     \
    BAR(); LGKM0(); MFQ(0, 1, bf1h); BAR();                                 \
    /* ph3 */                                                               \
    READ_A(1, 0); if (E) STAGE(1, 1, 0, (knext));                           \
    BAR(); LGKM0(); MFQ(1, 1, bf1h); BAR();                                 \
    /* ph4 (B0 held in bf0h: no re-read) */                                 \
    if (E) { STAGE(0, 1, 0, (knext)); VMC6(); } else { VMC0(); }            \
    BAR(); LGKM0(); MFQ(1, 0, bf0h); BAR();                                 \
    /* ph5 */                                                               \
    READ_A(0, 65536); READ_B(bf0h, 0, 65536); if (E) STAGE(1, 0, 0, (knext)); \
    BAR(); LGKM0(); MFQ(0, 0, bf0h); BAR();                                 \
    /* ph6 */                                                               \
    READ_B(bf1h, 1, 65536); if (E) STAGE(0, 0, 1, (knext) + 64);            \
    BAR(); LGKM0(); MFQ(0, 1, bf1h); BAR();                                 \
    /* ph7 */                                                               \
    READ_A(1, 65536); if (E) STAGE(1, 1, 1, (knext) + 64);                  \
    BAR(); LGKM0(); MFQ(1, 1, bf1h); BAR();                                 \
    /* ph8 (B0 held) */                                                     \
    if (E) { STAGE(0, 1, 1, (knext) + 64); VMC6(); }                        \
    BAR(); LGKM0(); MFQ(1, 0, bf0h); BAR();                                 \
} while (0)

    int it = 0;
    #pragma unroll 1
    for (; it < niters - 1; ++it) {
        const int kc = kb + it * 128;
        ITER(1, kc, kc + 128);
    }
    {   // last iteration: no next-tile staging, full drain at ph4
        const int kc = kb + it * 128;
        ITER(0, kc, 0);
    }

#undef ITER
#undef LDSV
#undef READ_A
#undef READ_B
#undef STAGE
#undef MFQ
#undef BAR
#undef LGKM0
#undef VMC6
#undef VMC0

    // ---- epilogue (round-1 verified direct stores) ----
    // row = bm*256 + wm*128 + (i>>2)*64 + (i&3)*16 + lq*4 + r
    // col = bn*256 + (wn>>1)*128 + (j>>1)*64 + (wn&1)*32 + (j&1)*16 + lm
    if (EPI == 2) {
        #pragma unroll
        for (int i = 0; i < 8; i++) {
            const int grow0 = bm * 256 + wm * 128 + (i >> 2) * 64 + (i & 3) * 16 + lq * 4;
            #pragma unroll
            for (int r = 0; r < 4; r++) {
                float rs = 0.f;
                #pragma unroll
                for (int j = 0; j < 4; j++) {
                    const int gcol = bn * 256 + (wn >> 1) * 128 + (j >> 1) * 64 +
                                     (wn & 1) * 32 + (j & 1) * 16 + lm;
                    float e = __expf(acc[i][j][r] * scale);
                    unsigned short eb = f2b_bits(e);
                    ((unsigned short*)outH)[(size_t)(grow0 + r) * N + gcol] = eb;
                    rs += b2f_bits(eb);
                }
                rs += __shfl_xor(rs, 1, 64);
                rs += __shfl_xor(rs, 2, 64);
                rs += __shfl_xor(rs, 4, 64);
                rs += __shfl_xor(rs, 8, 64);
                if (lm == 0)
                    ps[(size_t)(grow0 + r) * PS_COLS + bn * 4 + wn] = rs;
            }
        }
    } else {
        __hip_bfloat16* outHz = outH + ((EPI == 4) ? (size_t)blockIdx.z * M * N : 0);
        #pragma unroll
        for (int i = 0; i < 8; i++) {
            const int grow0 = bm * 256 + wm * 128 + (i >> 2) * 64 + (i & 3) * 16 + lq * 4;
            #pragma unroll
            for (int j = 0; j < 4; j++) {
                const int gcol = bn * 256 + (wn >> 1) * 128 + (j >> 1) * 64 +
                                 (wn & 1) * 32 + (j & 1) * 16 + lm;
                #pragma unroll
                for (int r = 0; r < 4; r++) {
                    float v = acc[i][j][r];
                    size_t idx = (size_t)(grow0 + r) * N + gcol;
                    if (EPI == 1) outHz[idx] = __float2bfloat16(v + biasSel[gcol]);
                    else          outHz[idx] = __float2bfloat16(v * scale);
                }
            }
        }
    }
}

// ------- final: out[row] = (sum of bf16 partials) / (sum of ps[row][*]) -------
__global__ __launch_bounds__(256) void reduce4_k(const ushortx4* __restrict__ part,
                                                 const float* __restrict__ ps,
                                                 float4* __restrict__ out) {
    int row = blockIdx.x;
    float s = 0.f;
    if (threadIdx.x < PS_COLS) s = ps[(size_t)row * PS_COLS + threadIdx.x];
    float tot = blockReduceSum(s);
    float inv = 1.f / tot;
    size_t base = (size_t)row * (HDIM / 4) + threadIdx.x;
    const size_t stride = (size_t)BS_CAND * (HDIM / 4);
    float4 o = {0.f, 0.f, 0.f, 0.f};
    #pragma unroll
    for (int z = 0; z < PV_SPLIT; z++) {
        ushortx4 p = part[base + (size_t)z * stride];
        o.x += b2f_bits(p.x); o.y += b2f_bits(p.y);
        o.z += b2f_bits(p.z); o.w += b2f_bits(p.w);
    }
    o.x *= inv; o.y *= inv; o.z *= inv; o.w *= inv;
    out[(size_t)row * (HDIM / 4) + threadIdx.x] = o;
}

// ---------------- launch ----------------
extern "C" void kernel_launch(void* const* d_in, const int* in_sizes, int n_in,
                              void* d_out, int out_size, void* d_ws, size_t ws_size,
                              hipStream_t stream) {
    const float* hidden = (const float*)d_in[0];   // [2,2048,1024]
    const float* membuf = (const float*)d_in[1];   // [8192,1024]
    const float* imp    = (const float*)d_in[2];   // [8192]
    const float* Wq     = (const float*)d_in[3];   // [1024,1024]
    const float* bq     = (const float*)d_in[4];   // [1024]
    const float* Wk     = (const float*)d_in[5];   // [1024,1024]
    const float* bk     = (const float*)d_in[6];   // [1024]
    const float* noise  = (const float*)d_in[7];   // [8192]

    // 128 KiB dynamic LDS needs the opt-in attribute (once per process)
    static bool s_attr = false;
    if (!s_attr) {
        (void)hipFuncSetAttribute((const void*)gemm_bt<1, 0>,
                                  hipFuncAttributeMaxDynamicSharedMemorySize, 131072);
        (void)hipFuncSetAttribute((const void*)gemm_bt<2, 0>,
                                  hipFuncAttributeMaxDynamicSharedMemorySize, 131072);
        (void)hipFuncSetAttribute((const void*)gemm_bt<4, 1>,
                                  hipFuncAttributeMaxDynamicSharedMemorySize, 131072);
        s_attr = true;
    }

    char* ws = (char*)d_ws;
    size_t off = 0;
    auto alloc = [&](size_t bytes) -> void* {
        void* p = ws + off;
        off += (bytes + 255) & ~(size_t)255;
        return p;
    };
    // --- persistent region (front) ---
    float*          surprise = (float*)alloc(BS_CAND * 4);
    float*          skeys    = (float*)alloc(MSLOTS * 4);
    float*          ps       = (float*)alloc((size_t)BS_CAND * PS_COLS * 4);   // 2 MB
    int*            cand_ord = (int*)alloc(BS_CAND * 4);
    int*            slot_ord = (int*)alloc(MSLOTS * 4);
    int*            row_src  = (int*)alloc(MSLOTS * 4);
    __hip_bfloat16* Wqbf = (__hip_bfloat16*)alloc((size_t)HDIM * HDIM * 2);    // 2 MB
    __hip_bfloat16* Wkbf = (__hip_bfloat16*)alloc((size_t)HDIM * HDIM * 2);    // 2 MB
    __hip_bfloat16* BbfT = (__hip_bfloat16*)alloc((size_t)HDIM * MSLOTS * 2);  // 16 MB
    // --- Sbf region (64 MB), overlaid with Hbf (8 MB) + Bbf (16 MB), which are
    // CONTIGUOUS (A = [H; B] for the fused projection GEMM) and die before the
    // scores GEMM writes Sbf ---
    size_t s_base = off;
    __hip_bfloat16* Sbf = (__hip_bfloat16*)(ws + s_base);                      // 64 MB
    __hip_bfloat16* Hbf = (__hip_bfloat16*)(ws + s_base);                      //  8 MB
    __hip_bfloat16* Bbf = (__hip_bfloat16*)(ws + s_base + (size_t)BS_CAND * HDIM * 2);
    off = s_base + ((size_t)BS_CAND * MSLOTS * 2 + 255) & ~(size_t)255;
    // --- tail region: qbf+mkbf CONTIGUOUS; PV partials overlay them later ---
    size_t t_base = off;
    __hip_bfloat16* qbf  = (__hip_bfloat16*)alloc((size_t)BS_CAND * HDIM * 2); // 8 MB
    __hip_bfloat16* mkbf = (__hip_bfloat16*)alloc((size_t)MSLOTS * HDIM * 2);  // 16 MB
    __hip_bfloat16* part = (__hip_bfloat16*)(ws + t_base);  // 4 x 8 MB bf16 partials

    // 1) merged prologue: hidden norm+cast | slot keys | Wq/Wk cast
    pre_k<<<BS_CAND + MSLOTS / 256 + 2048, 256, 0, stream>>>(
        hidden, surprise, Hbf, imp, noise, skeys, row_src, Wq, Wqbf, Wk, Wkbf);
    // 2) both rankings: 4 elems/block, register counters
    ranks_k<<<(BS_CAND + MSLOTS) / 4, 256, 0, stream>>>(
        surprise, cand_ord, skeys, slot_ord);
    scatter_k<<<BS_CAND / 256, 256, 0, stream>>>(cand_ord, slot_ord, surprise, row_src);
    // 3) updated memory buffer + its transpose, fused one-pass
    bbt_k<<<dim3(HDIM / 64, MSLOTS / 64), 256, 0, stream>>>(
        membuf, hidden, row_src, Bbf, BbfT);
    // 4) fused projections: [q; mk] = [H; newbuf] @ {Wq,Wk}^T + {bq,bk}
    gemm_bt<1, 0><<<dim3(HDIM / 256, (BS_CAND + MSLOTS) / 256), 512, 131072, stream>>>(
        Hbf, Wqbf, Wkbf, qbf, bq, bk, nullptr, BS_CAND / 256,
        BS_CAND + MSLOTS, HDIM, HDIM, HDIM, 1.f);
    // 5) E = bf16(exp((q @ mk^T)/32)) + per-wave strip sums into ps
    gemm_bt<2, 0><<<dim3(MSLOTS / 256, BS_CAND / 256), 512, 131072, stream>>>(
        qbf, mkbf, nullptr, Sbf, nullptr, nullptr, ps, 1 << 30,
        BS_CAND, MSLOTS, HDIM, HDIM, 0.03125f);
    // 6) split-K PV: bf16 partial[z] = E @ newbuf over K-chunk z
    gemm_bt<4, 1><<<dim3(BS_CAND / 256, HDIM / 256, PV_SPLIT), 512, 131072, stream>>>(
        Sbf, BbfT, nullptr, part, nullptr, nullptr, nullptr, 1 << 30,
        BS_CAND, HDIM, MSLOTS, MSLOTS / PV_SPLIT, 1.f);
    // 7) out = (sum of 4 bf16 partials) / rowsum(ps)   -> fp32 [4096,1024]
    reduce4_k<<<BS_CAND, 256, 0, stream>>>((const ushortx4*)part, ps, (float4*)d_out);
}